// Round 6
// baseline (363.734 us; speedup 1.0000x reference)
//
#include <hip/hip_runtime.h>
#include <hip/hip_bf16.h>
#include <math.h>

// Problem constants (b=4,h=8,t=8192,d=64, c=64 clusters, wsz=128)
#define NB 4
#define NH 8
#define TT 8192
#define DD 64
#define NC 64
#define WW 128
#define BHN 32            // NB*NH
#define SCALE 0.125f      // d^-0.5
#define INVCAP 24         // max tracked clusters per token
#define DTPB 64           // tokens per k_dists block

typedef __bf16  bf16x8 __attribute__((ext_vector_type(8)));
typedef __bf16  bf16x4 __attribute__((ext_vector_type(4)));
typedef float   f32x4  __attribute__((ext_vector_type(4)));
typedef unsigned long long u64;
typedef unsigned int u32;

#define MFMA(a, b, c) __builtin_amdgcn_mfma_f32_16x16x32_bf16((a), (b), (c), 0, 0, 0)

// monotone u32 key from float: unsigned compare == float total order
__device__ __forceinline__ u32 monokey(float f) {
    const u32 u = __float_as_uint(f);
    return u ^ (((u32)((int)u >> 31)) | 0x80000000u);
}

// ---------------------------------------------------------------------------
// Kernel 1: routing dists via error-compensated bf16 MFMA -> monotone u32
// keys (+ loss). Block: 64 tokens x 64 clusters, 4 waves (1 token-tile each).
// Means split f32->3xbf16 INLINE; by==0 blocks also pre-cast rel_w -> bf16.
// ---------------------------------------------------------------------------
#define QD_ADDR(row, gi) (((row) << 6) + ((((gi) ^ ((row) & 7))) << 3))

__global__ __launch_bounds__(256) void k_dists(
    const float* __restrict__ qk, const float* __restrict__ means,
    const float* __restrict__ rel_w, __bf16* __restrict__ relb,
    u32* __restrict__ keys, double* __restrict__ lossa)
{
    __shared__ __attribute__((aligned(16))) __bf16 qh[64 * 64], qm[64 * 64], ql[64 * 64];
    __shared__ __attribute__((aligned(16))) __bf16 ah[64 * 64], am[64 * 64], al[64 * 64];
    __shared__ float invS[DTPB], s2S[DTPB], mn2S[NC];
    __shared__ double red[4];

    const int bh = blockIdx.x, h = bh & 7, tid = threadIdx.x;
    const int t0 = blockIdx.y * DTPB;

    // rel_w -> bf16 cast (32 by==0 blocks cover 16384 float4 groups)
    if (blockIdx.y == 0) {
        const float4* rw = (const float4*)rel_w;
#pragma unroll
        for (int k = 0; k < 2; k++) {
            const int i = bh * 512 + k * 256 + tid;
            const float4 v = rw[i];
            bf16x4 o;
            o[0] = (__bf16)v.x; o[1] = (__bf16)v.y; o[2] = (__bf16)v.z; o[3] = (__bf16)v.w;
            *(bf16x4*)(relb + i * 4) = o;
        }
    }

    // stage means: f32 -> 3-way bf16 split (swizzled) + row norms^2
    {
        const int r = tid >> 2, qt = tid & 3;        // row 0..63, 16-float seg
        const float4* src = (const float4*)(means + (size_t)(h * NC + r) * DD + qt * 16);
        float4 f[4];
        f[0] = src[0]; f[1] = src[1]; f[2] = src[2]; f[3] = src[3];
        bf16x8 vh[2], vm[2], vl[2];
        float ssq = 0.f;
#pragma unroll
        for (int j = 0; j < 16; j++) {
            const float xx = ((const float*)f)[j];
            ssq = fmaf(xx, xx, ssq);
            const __bf16 hh_ = (__bf16)xx;
            const float r1 = xx - (float)hh_;
            const __bf16 mm_ = (__bf16)r1;
            const float r2 = r1 - (float)mm_;
            vh[j >> 3][j & 7] = hh_; vm[j >> 3][j & 7] = mm_; vl[j >> 3][j & 7] = (__bf16)r2;
        }
#pragma unroll
        for (int gg = 0; gg < 2; gg++) {
            const int dst = QD_ADDR(r, qt * 2 + gg);
            *(bf16x8*)(ah + dst) = vh[gg];
            *(bf16x8*)(am + dst) = vm[gg];
            *(bf16x8*)(al + dst) = vl[gg];
        }
        ssq += __shfl_xor(ssq, 1);
        ssq += __shfl_xor(ssq, 2);
        if (qt == 0) mn2S[r] = ssq;
    }
    // stage qk: split into 3 bf16 tiles + fp32 norms
    {
        const int r = tid >> 2, qt = tid & 3;        // row, 16-float segment
        const float4* src = (const float4*)(qk + ((size_t)bh * TT + t0 + r) * DD + qt * 16);
        float4 f[4];
        f[0] = src[0]; f[1] = src[1]; f[2] = src[2]; f[3] = src[3];
        bf16x8 vh[2], vm[2], vl[2];
        float ssq = 0.f;
#pragma unroll
        for (int j = 0; j < 16; j++) {
            const float xx = ((const float*)f)[j];
            ssq = fmaf(xx, xx, ssq);
            const __bf16 hh_ = (__bf16)xx;
            const float r1 = xx - (float)hh_;
            const __bf16 mm_ = (__bf16)r1;
            const float r2 = r1 - (float)mm_;
            vh[j >> 3][j & 7] = hh_; vm[j >> 3][j & 7] = mm_; vl[j >> 3][j & 7] = (__bf16)r2;
        }
#pragma unroll
        for (int gg = 0; gg < 2; gg++) {
            const int dst = QD_ADDR(r, qt * 2 + gg);
            *(bf16x8*)(qh + dst) = vh[gg];
            *(bf16x8*)(qm + dst) = vm[gg];
            *(bf16x8*)(ql + dst) = vl[gg];
        }
        ssq += __shfl_xor(ssq, 1);
        ssq += __shfl_xor(ssq, 2);
        if (qt == 0) {
            const float inv = 1.0f / fmaxf(sqrtf(ssq), 1e-12f);
            invS[r] = inv;
            s2S[r] = ssq * inv * inv;
        }
    }
    __syncthreads();

    const int lane = tid & 63, wv = tid >> 6;
    const int lo = lane & 15, quad = lane >> 4;

    // B-frags: this wave's token tile (col = lo, k = quad*8 + kh*32)
    bf16x8 Bh[2], Bm[2], Bl[2];
    {
        const int row = wv * 16 + lo;
#pragma unroll
        for (int kh = 0; kh < 2; kh++) {
            const int src = QD_ADDR(row, kh * 4 + quad);
            Bh[kh] = *(const bf16x8*)(qh + src);
            Bm[kh] = *(const bf16x8*)(qm + src);
            Bl[kh] = *(const bf16x8*)(ql + src);
        }
    }

    f32x4 acc[4];
#pragma unroll
    for (int ct = 0; ct < 4; ct++) {
        bf16x8 Ah[2], Am[2], Al[2];
#pragma unroll
        for (int kh = 0; kh < 2; kh++) {
            const int src = QD_ADDR(ct * 16 + lo, kh * 4 + quad);
            Ah[kh] = *(const bf16x8*)(ah + src);
            Am[kh] = *(const bf16x8*)(am + src);
            Al[kh] = *(const bf16x8*)(al + src);
        }
        f32x4 a = (f32x4){0.f, 0.f, 0.f, 0.f};
        // ~2^-24 terms
        a = MFMA(Al[0], Bm[0], a); a = MFMA(Al[1], Bm[1], a);
        a = MFMA(Am[0], Bl[0], a); a = MFMA(Am[1], Bl[1], a);
        // ~2^-16 terms
        a = MFMA(Am[0], Bm[0], a); a = MFMA(Am[1], Bm[1], a);
        a = MFMA(Ah[0], Bl[0], a); a = MFMA(Ah[1], Bl[1], a);
        a = MFMA(Al[0], Bh[0], a); a = MFMA(Al[1], Bh[1], a);
        // ~2^-8 terms
        a = MFMA(Am[0], Bh[0], a); a = MFMA(Am[1], Bh[1], a);
        a = MFMA(Ah[0], Bm[0], a); a = MFMA(Ah[1], Bm[1], a);
        // main term
        a = MFMA(Ah[0], Bh[0], a); a = MFMA(Ah[1], Bh[1], a);
        acc[ct] = a;
    }

    // epilogue: keys + per-token argmax (for loss only)
    const int tok = wv * 16 + lo;
    const float inv = invS[tok];
    float rawmax = -3.0e38f; int cbest = 0;
    u32* kout = keys + (size_t)bh * NC * TT + (size_t)(t0 + tok);
#pragma unroll
    for (int ct = 0; ct < 4; ct++)
#pragma unroll
        for (int r = 0; r < 4; r++) {
            const float raw = acc[ct][r];
            const int c = ct * 16 + quad * 4 + r;
            if (raw > rawmax) { rawmax = raw; cbest = c; }
            kout[(size_t)c * TT] = monokey(raw * inv);
        }

    // merge argmax across quads (lanes lo+16q share token lo)
#pragma unroll
    for (int off = 16; off < 64; off <<= 1) {
        const float ov = __shfl_xor(rawmax, off);
        const int   oc = __shfl_xor(cbest, off);
        if (ov > rawmax || (ov == rawmax && oc < cbest)) { rawmax = ov; cbest = oc; }
    }
    double lt_lane = 0.0;
    if (quad == 0)
        lt_lane = (double)(s2S[tok] + mn2S[cbest] - 2.0f * rawmax * inv);

    // block loss reduction
#pragma unroll
    for (int o = 32; o; o >>= 1) lt_lane += __shfl_xor(lt_lane, o);
    if (lane == 0) red[wv] = lt_lane;
    __syncthreads();
    if (tid == 0) atomicAdd(lossa, red[0] + red[1] + red[2] + red[3]);
}

// ---------------------------------------------------------------------------
// Kernel 2: top-128 per (bh,c), 8-bit radix select on u32 monotone keys.
// ---------------------------------------------------------------------------
__global__ __launch_bounds__(256) void k_topk(
    const u32* __restrict__ keys, int* __restrict__ indices,
    unsigned int* __restrict__ cnt, unsigned short* __restrict__ inv)
{
    __shared__ unsigned int hist[4][256];    // 4 KB
    __shared__ int wsum[8];
    __shared__ int bc_bin, bc_rank, bc_cnt;

    const int bhc = blockIdx.x, tid = threadIdx.x;
    const int wv = tid >> 6, lane = tid & 63;
    const int bh = bhc >> 6;

    u32 key[32];
    {
        const uint4* p = (const uint4*)(keys + (size_t)bhc * TT + tid * 32);
#pragma unroll
        for (int i = 0; i < 8; i++) {
            uint4 u = p[i];
            key[4*i] = u.x; key[4*i+1] = u.y; key[4*i+2] = u.z; key[4*i+3] = u.w;
        }
    }

    u32 thr = 0;
    int need = 128, gshift = 24, prevShift = 0;
    unsigned int* hb = &hist[0][0];

    for (int level = 0; level < 4; level++) {
        const int shift = 24 - 8 * level;
        hb[tid] = 0; hb[tid + 256] = 0; hb[tid + 512] = 0; hb[tid + 768] = 0;
        __syncthreads();
        unsigned int* hw = hist[wv];
        if (level == 0) {
#pragma unroll
            for (int i = 0; i < 32; i++)
                atomicAdd(&hw[key[i] >> 24], 1u);
        } else {
            const u32 pv = thr >> prevShift;
#pragma unroll
            for (int i = 0; i < 32; i++)
                if ((key[i] >> prevShift) == pv)
                    atomicAdd(&hw[(key[i] >> shift) & 255u], 1u);
        }
        __syncthreads();

        const int b = 255 - tid;
        const int c = hist[0][b] + hist[1][b] + hist[2][b] + hist[3][b];
        int incl = c;
#pragma unroll
        for (int o = 1; o < 64; o <<= 1) {
            const int v = __shfl_up(incl, o);
            if (lane >= o) incl += v;
        }
        if (lane == 63) wsum[wv] = incl;
        __syncthreads();
        int above = incl - c;
        for (int wj = 0; wj < wv; wj++) above += wsum[wj];
        if (above < need && above + c >= need) {
            bc_bin = b; bc_rank = above; bc_cnt = c;
        }
        __syncthreads();
        thr |= ((u32)bc_bin) << shift;
        need -= bc_rank;
        gshift = shift;
        prevShift = shift;
        if (bc_cnt == need || shift == 0) break;
    }

    // ordered emission + inverse map
    const u32 tg = thr >> gshift;
    int cgt = 0, ceq = 0;
#pragma unroll
    for (int i = 0; i < 32; i++) {
        const u32 kg = key[i] >> gshift;
        cgt += (kg > tg) ? 1 : 0;
        ceq += (kg == tg) ? 1 : 0;
    }
    int ig = cgt, ie = ceq;
#pragma unroll
    for (int o = 1; o < 64; o <<= 1) {
        const int vg = __shfl_up(ig, o);
        const int ve = __shfl_up(ie, o);
        if (lane >= o) { ig += vg; ie += ve; }
    }
    if (lane == 63) { wsum[wv] = ig; wsum[4 + wv] = ie; }
    __syncthreads();
    int pgt = ig - cgt, peq = ie - ceq;
    for (int wj = 0; wj < wv; wj++) { pgt += wsum[wj]; peq += wsum[4 + wj]; }

    const int rneed = need;
    int* outp = indices + bhc * WW;
    unsigned int* cntb = cnt + (bh << 13);
    unsigned short* invb = inv + (((size_t)bh << 13) * INVCAP);
    const int cbase = (bhc & 63) * WW;
    int g = 0, e = 0;
#pragma unroll
    for (int i = 0; i < 32; i++) {
        const int tok = tid * 32 + i;
        const u32 kg = key[i] >> gshift;
        if (kg > tg) {
            const int tb = (peq + e < rneed) ? (peq + e) : rneed;
            const int wpos = pgt + g + tb;
            outp[wpos] = tok;
            const unsigned int pos = atomicAdd(&cntb[tok], 1u);
            if (pos < INVCAP) invb[(size_t)tok * INVCAP + pos] = (unsigned short)(cbase + wpos);
            g++;
        } else if (kg == tg) {
            if (peq + e < rneed) {
                const int wpos = pgt + g + peq + e;
                outp[wpos] = tok;
                const unsigned int pos = atomicAdd(&cntb[tok], 1u);
                if (pos < INVCAP) invb[(size_t)tok * INVCAP + pos] = (unsigned short)(cbase + wpos);
            }
            e++;
        }
    }
}

// ---------------------------------------------------------------------------
// Kernel 3: per-(bh,c) local attention, MFMA bf16. 512 threads = 8 waves.
// LDS diet: R packed as upper triangle (8256 elems), PV split in two K-halves
// with per-wave P-half buffer (stride 72). Unions {qs->Phalf} + {rp->vt}
// = 36352 B -> 4 blocks/CU (32 waves). Same 3 barriers as before; all
// P-half and rp accesses are wave-internal (no extra syncs needed).
// ---------------------------------------------------------------------------
#define QS_ADDR(row, gi) (((row) << 6) + ((((gi) ^ ((row) & 7))) << 3))

__global__ __launch_bounds__(512, 8) void k_attn(
    const float* __restrict__ qk, const float* __restrict__ vin,
    const __bf16* __restrict__ relb, const int* __restrict__ indices,
    float* __restrict__ bo)
{
    __shared__ __attribute__((aligned(16))) __bf16 u1[128 * 72];   // qs (swz, stride 64) -> P half (stride 72)
    __shared__ __attribute__((aligned(16))) __bf16 u2[64 * 136];   // rp packed triangle -> v^T (stride 136)
    __shared__ float invs[128];

    const int tid  = threadIdx.x;
    const int lane = tid & 63;
    const int wv   = tid >> 6;
    const int lo   = lane & 15;
    const int quad = lane >> 4;
    const int rbase = wv * 16;

    const int bhc = blockIdx.x;
    const int bh  = bhc >> 6;
    const int h   = bh & 7;

    // ---- q gather, v prefetch in regs (row index straight from global) ----
    const int r  = tid >> 2;          // row 0..127
    const int qp = tid & 3;           // 16-float segment
    const int rowidx = indices[bhc * WW + r];
    const size_t rowoff = ((size_t)bh * TT + rowidx) * DD + qp * 16;
    float4 vreg[4];
    {
        float4 q0, q1, q2, q3;
        const float4* qsrc = (const float4*)(qk + rowoff);
        q0 = qsrc[0]; q1 = qsrc[1]; q2 = qsrc[2]; q3 = qsrc[3];
        const float4* vsrc = (const float4*)(vin + rowoff);
        vreg[0] = vsrc[0]; vreg[1] = vsrc[1]; vreg[2] = vsrc[2]; vreg[3] = vsrc[3];

        float ssq = q0.x*q0.x + q0.y*q0.y + q0.z*q0.z + q0.w*q0.w
                  + q1.x*q1.x + q1.y*q1.y + q1.z*q1.z + q1.w*q1.w
                  + q2.x*q2.x + q2.y*q2.y + q2.z*q2.z + q2.w*q2.w
                  + q3.x*q3.x + q3.y*q3.y + q3.z*q3.z + q3.w*q3.w;
        ssq += __shfl_xor(ssq, 1);
        ssq += __shfl_xor(ssq, 2);
        if (qp == 0) invs[r] = 1.0f / fmaxf(sqrtf(ssq), 1e-12f);
        bf16x8 va, vb;
        va[0]=(__bf16)q0.x; va[1]=(__bf16)q0.y; va[2]=(__bf16)q0.z; va[3]=(__bf16)q0.w;
        va[4]=(__bf16)q1.x; va[5]=(__bf16)q1.y; va[6]=(__bf16)q1.z; va[7]=(__bf16)q1.w;
        vb[0]=(__bf16)q2.x; vb[1]=(__bf16)q2.y; vb[2]=(__bf16)q2.z; vb[3]=(__bf16)q2.w;
        vb[4]=(__bf16)q3.x; vb[5]=(__bf16)q3.y; vb[6]=(__bf16)q3.z; vb[7]=(__bf16)q3.w;
        *(bf16x8*)(u1 + QS_ADDR(r, qp * 2))     = va;
        *(bf16x8*)(u1 + QS_ADDR(r, qp * 2 + 1)) = vb;
    }
    __syncthreads();   // S1: qs + invs complete

    f32x4 acc[8];

    // ---- R = Q * W^T -> packed upper triangle rp[i(i+1)/2 + j] ----
#pragma unroll
    for (int nt = 0; nt < 8; nt++) acc[nt] = (f32x4){0.f, 0.f, 0.f, 0.f};
#pragma unroll
    for (int k0 = 0; k0 < 64; k0 += 32) {
        bf16x8 qa = *(const bf16x8*)(u1 + QS_ADDR(rbase + lo, (k0 >> 3) + quad));
#pragma unroll
        for (int nt = 0; nt < 8; nt++) {
            const bf16x8 wb = *(const bf16x8*)(relb + ((nt * 16 + lo) * 8 + h) * 64 + k0 + quad * 8);
            acc[nt] = MFMA(qa, wb, acc[nt]);
        }
    }
    // element (i, jj=nt*16+lo): bias needs jj >= 127-i -> packed[i(i+1)/2 + (jj-127+i)]
#pragma unroll
    for (int nt = 0; nt < 8; nt++)
#pragma unroll
        for (int rg = 0; rg < 4; rg++) {
            const int i = rbase + quad * 4 + rg;
            const int jsrc = nt * 16 + lo - 127 + i;
            if (jsrc >= 0)
                u2[((i * (i + 1)) >> 1) + jsrc] = (__bf16)acc[nt][rg];
        }

    // ---- dots = (Q*Q^T) * inv_j * scale ----
#pragma unroll
    for (int nt = 0; nt < 8; nt++) acc[nt] = (f32x4){0.f, 0.f, 0.f, 0.f};
#pragma unroll
    for (int k0 = 0; k0 < 64; k0 += 32) {
        bf16x8 qa = *(const bf16x8*)(u1 + QS_ADDR(rbase + lo, (k0 >> 3) + quad));
#pragma unroll
        for (int nt = 0; nt < 8; nt++) {
            bf16x8 qb = *(const bf16x8*)(u1 + QS_ADDR(nt * 16 + lo, (k0 >> 3) + quad));
            acc[nt] = MFMA(qa, qb, acc[nt]);
        }
    }

    // bias (packed triangle read, wave-internal) + self-mask
#pragma unroll
    for (int rg = 0; rg < 4; rg++) {
        const int i = rbase + quad * 4 + rg;
        const int off = (i * (i + 1)) >> 1;
#pragma unroll
        for (int nt = 0; nt < 8; nt++) {
            const int j = nt * 16 + lo;
            float val = acc[nt][rg] * invs[j] * SCALE;
            if (j <= i) val += SCALE * (float)u2[off + j];
            if (j == i) val = -50000.0f;
            acc[nt][rg] = val;
        }
    }

    // row softmax (fully in registers; P stays in acc)
#pragma unroll
    for (int rg = 0; rg < 4; rg++) {
        float m = -3.0e38f;
#pragma unroll
        for (int nt = 0; nt < 8; nt++) m = fmaxf(m, acc[nt][rg]);
#pragma unroll
        for (int msk = 1; msk < 16; msk <<= 1) m = fmaxf(m, __shfl_xor(m, msk));
        float s = 0.f;
#pragma unroll
        for (int nt = 0; nt < 8; nt++) {
            const float e = __expf(acc[nt][rg] - m);
            acc[nt][rg] = e; s += e;
        }
#pragma unroll
        for (int msk = 1; msk < 16; msk <<= 1) s += __shfl_xor(s, msk);
        const float is = 1.0f / s;
#pragma unroll
        for (int nt = 0; nt < 8; nt++) acc[nt][rg] *= is;
    }
    __syncthreads();   // S2: all qs reads (QK) + rp reads (bias) done

    // ---- v (from regs) transposed into u2: vt[d][j], stride 136 ----
    __bf16* vt = u2;
#pragma unroll
    for (int i = 0; i < 4; i++) {
        vt[(qp * 16 + 4*i + 0) * 136 + r] = (__bf16)vreg[i].x;
        vt[(qp * 16 + 4*i + 1) * 136 + r] = (__bf16)vreg[i].y;
        vt[(qp * 16 + 4*i + 2) * 136 + r] = (__bf16)vreg[i].z;
        vt[(qp * 16 + 4*i + 3) * 136 + r] = (__bf16)vreg[i].w;
    }
    // ---- P half 1 (j=0..63) into u1, stride 72 (wave-internal rows) ----
#pragma unroll
    for (int nt = 0; nt < 4; nt++)
#pragma unroll
        for (int rg = 0; rg < 4; rg++)
            u1[(rbase + quad * 4 + rg) * 72 + nt * 16 + lo] = (__bf16)acc[nt][rg];
    __syncthreads();   // S3: vt complete (cross-wave); P half1 in place

    // ---- bo = P * V, K-half 1 (j=0..63) ----
    f32x4 accO[4];
#pragma unroll
    for (int nt = 0; nt < 4; nt++) accO[nt] = (f32x4){0.f, 0.f, 0.f, 0.f};
#pragma unroll
    for (int k0 = 0; k0 < 64; k0 += 32) {
        bf16x8 pa = *(const bf16x8*)(u1 + (rbase + lo) * 72 + k0 + quad * 8);
#pragma unroll
        for (int nt = 0; nt < 4; nt++) {
            bf16x8 vb = *(const bf16x8*)(vt + (nt * 16 + lo) * 136 + k0 + quad * 8);
            accO[nt] = MFMA(pa, vb, accO[nt]);
        }
    }

    // ---- P half 2 (j=64..127) overwrites half 1 (wave-internal) ----
#pragma unroll
    for (int nt = 4; nt < 8; nt++)
#pragma unroll
        for (int rg = 0; rg < 4; rg++)
            u1[(rbase + quad * 4 + rg) * 72 + (nt - 4) * 16 + lo] = (__bf16)acc[nt][rg];

    // ---- bo = P * V, K-half 2 (j=64..127), accumulate ----
#pragma unroll
    for (int k0 = 0; k0 < 64; k0 += 32) {
        bf16x8 pa = *(const bf16x8*)(u1 + (rbase + lo) * 72 + k0 + quad * 8);
#pragma unroll
        for (int nt = 0; nt < 4; nt++) {
            bf16x8 vb = *(const bf16x8*)(vt + (nt * 16 + lo) * 136 + 64 + k0 + quad * 8);
            accO[nt] = MFMA(pa, vb, accO[nt]);
        }
    }

    // ---- dense store ----
    float* bb = bo + (size_t)bhc * (WW * DD);
#pragma unroll
    for (int rg = 0; rg < 4; rg++) {
        const int i = rbase + quad * 4 + rg;
#pragma unroll
        for (int nt = 0; nt < 4; nt++)
            bb[(size_t)i * DD + nt * 16 + lo] = accO[nt][rg];
    }
}

// ---------------------------------------------------------------------------
// Kernel 4: per-token gather-sum of dense bo rows + normalize (+ loss).
// Slots 0..7 prefetched via one 16-B load -> up to 8 INDEPENDENT row gathers
// issue in parallel (was a serial dependent chain). Tail loop only for nc>8.
// ---------------------------------------------------------------------------
__global__ __launch_bounds__(256) void k_out(
    const float* __restrict__ bo, const unsigned int* __restrict__ cnt,
    const unsigned short* __restrict__ inv, const double* __restrict__ lossa,
    float* __restrict__ out)
{
    const int tid = threadIdx.x;
    const int g = blockIdx.x * 16 + (tid >> 4);      // global token 0..262143
    const int l = tid & 15;
    const int bh = g >> 13;
    const unsigned int n = cnt[g];
    const int nc = (n < (unsigned)INVCAP) ? (int)n : INVCAP;
    const unsigned short* ip = inv + (size_t)g * INVCAP;
    const float* bbase = bo + (((size_t)bh << 13) * DD) + l * 4;

    // prefetch first 8 slot ids in one 16-B load (inv rows are 48 B, 16-aligned)
    const uint4 ipv = *(const uint4*)ip;
    const int s0 = ipv.x & 0xffff, s1 = ipv.x >> 16;
    const int s2 = ipv.y & 0xffff, s3 = ipv.y >> 16;
    const int s4 = ipv.z & 0xffff, s5 = ipv.z >> 16;
    const int s6 = ipv.w & 0xffff, s7 = ipv.w >> 16;

    float4 a0 = {0.f,0.f,0.f,0.f}, a1 = a0, a2 = a0, a3 = a0;
    float4 a4 = a0, a5 = a0, a6 = a0, a7 = a0;
    if (nc > 0) a0 = *(const float4*)(bbase + (size_t)s0 * DD);
    if (nc > 1) a1 = *(const float4*)(bbase + (size_t)s1 * DD);
    if (nc > 2) a2 = *(const float4*)(bbase + (size_t)s2 * DD);
    if (nc > 3) a3 = *(const float4*)(bbase + (size_t)s3 * DD);
    if (nc > 4) a4 = *(const float4*)(bbase + (size_t)s4 * DD);
    if (nc > 5) a5 = *(const float4*)(bbase + (size_t)s5 * DD);
    if (nc > 6) a6 = *(const float4*)(bbase + (size_t)s6 * DD);
    if (nc > 7) a7 = *(const float4*)(bbase + (size_t)s7 * DD);

    float4 s;
    s.x = ((a0.x + a1.x) + (a2.x + a3.x)) + ((a4.x + a5.x) + (a6.x + a7.x));
    s.y = ((a0.y + a1.y) + (a2.y + a3.y)) + ((a4.y + a5.y) + (a6.y + a7.y));
    s.z = ((a0.z + a1.z) + (a2.z + a3.z)) + ((a4.z + a5.z) + (a6.z + a7.z));
    s.w = ((a0.w + a1.w) + (a2.w + a3.w)) + ((a4.w + a5.w) + (a6.w + a7.w));

    for (int e = 8; e < nc; e++) {
        const int slot = ip[e];
        const float4 v4 = *(const float4*)(bbase + (size_t)slot * DD);
        s.x += v4.x; s.y += v4.y; s.z += v4.z; s.w += v4.w;
    }

    const float r = 1.0f / ((float)n + 1e-5f);
    s.x *= r; s.y *= r; s.z *= r; s.w *= r;
    *(float4*)(out + (size_t)g * DD + l * 4) = s;
    if (g == 0 && l == 0) out[16777216] = (float)(lossa[0] * (0.0001 / 16777216.0));
}

// ---------------------------------------------------------------------------
extern "C" void kernel_launch(void* const* d_in, const int* in_sizes, int n_in,
                              void* d_out, int out_size, void* d_ws, size_t ws_size,
                              hipStream_t stream) {
    (void)in_sizes; (void)n_in; (void)ws_size; (void)out_size;
    const float* qk    = (const float*)d_in[0];
    const float* v     = (const float*)d_in[1];
    const float* means = (const float*)d_in[2];
    const float* rel_w = (const float*)d_in[3];
    float* out = (float*)d_out;

    // ws layout:
    //   [keys u32 67MB]           (bo 67MB aliases it after k_topk)
    //   [idx 1MB]
    //   [cnt 1MB][lossa pad 4KB]  (memset region)
    //   [inv u16 cap24 12.6MB]
    //   [relb bf16 128KB]
    char* ws = (char*)d_ws;
    const size_t KEYS_B = (size_t)BHN * NC * TT * 4;        // 67108864
    const size_t IDX_B  = (size_t)BHN * NC * WW * 4;        // 1048576
    const size_t CNT_B  = (size_t)BHN * TT * 4;             // 1048576
    const size_t INV_B  = (size_t)BHN * TT * INVCAP * 2;    // 12582912
    u32*            keys  = (u32*)ws;
    float*          bo    = (float*)ws;                     // alias, post-k_topk
    int*            idx   = (int*)(ws + KEYS_B);
    unsigned int*   cnt   = (unsigned int*)(ws + KEYS_B + IDX_B);
    double*         lossa = (double*)(ws + KEYS_B + IDX_B + CNT_B);
    unsigned short* inv   = (unsigned short*)(ws + KEYS_B + IDX_B + CNT_B + 4096);
    __bf16*         relb  = (__bf16*)(ws + KEYS_B + IDX_B + CNT_B + 4096 + INV_B);

    hipMemsetAsync(ws + KEYS_B + IDX_B, 0, CNT_B + 4096, stream);

    k_dists<<<dim3(BHN, TT / DTPB), 256, 0, stream>>>(qk, means, rel_w, relb, keys, lossa);
    k_topk<<<BHN * NC, 256, 0, stream>>>(keys, idx, cnt, inv);
    k_attn<<<BHN * NC, 512, 0, stream>>>(qk, v, relb, idx, bo);
    k_out<<<BHN * TT / 16, 256, 0, stream>>>(bo, cnt, inv, lossa, out);
}

// Round 7
// 340.531 us; speedup vs baseline: 1.0681x; 1.0681x over previous
//
#include <hip/hip_runtime.h>
#include <hip/hip_bf16.h>
#include <math.h>

// Problem constants (b=4,h=8,t=8192,d=64, c=64 clusters, wsz=128)
#define NB 4
#define NH 8
#define TT 8192
#define DD 64
#define NC 64
#define WW 128
#define BHN 32            // NB*NH
#define SCALE 0.125f      // d^-0.5
#define INVCAP 24         // max tracked clusters per token
#define DTPB 64           // tokens per k_dists block

typedef __bf16  bf16x8 __attribute__((ext_vector_type(8)));
typedef __bf16  bf16x4 __attribute__((ext_vector_type(4)));
typedef float   f32x4  __attribute__((ext_vector_type(4)));
typedef unsigned long long u64;
typedef unsigned int u32;

#define MFMA(a, b, c) __builtin_amdgcn_mfma_f32_16x16x32_bf16((a), (b), (c), 0, 0, 0)

// monotone u32 key from float: unsigned compare == float total order
__device__ __forceinline__ u32 monokey(float f) {
    const u32 u = __float_as_uint(f);
    return u ^ (((u32)((int)u >> 31)) | 0x80000000u);
}

// ---------------------------------------------------------------------------
// Kernel 1: routing dists via error-compensated bf16 MFMA -> monotone u32
// keys (+ loss). Block: 64 tokens x 64 clusters, 4 waves (1 token-tile each).
// Means split f32->3xbf16 INLINE; by==0 blocks also pre-cast rel_w -> bf16.
// ---------------------------------------------------------------------------
#define QD_ADDR(row, gi) (((row) << 6) + ((((gi) ^ ((row) & 7))) << 3))

__global__ __launch_bounds__(256) void k_dists(
    const float* __restrict__ qk, const float* __restrict__ means,
    const float* __restrict__ rel_w, __bf16* __restrict__ relb,
    u32* __restrict__ keys, double* __restrict__ lossa)
{
    __shared__ __attribute__((aligned(16))) __bf16 qh[64 * 64], qm[64 * 64], ql[64 * 64];
    __shared__ __attribute__((aligned(16))) __bf16 ah[64 * 64], am[64 * 64], al[64 * 64];
    __shared__ float invS[DTPB], s2S[DTPB], mn2S[NC];
    __shared__ double red[4];

    const int bh = blockIdx.x, h = bh & 7, tid = threadIdx.x;
    const int t0 = blockIdx.y * DTPB;

    // rel_w -> bf16 cast (32 by==0 blocks cover 16384 float4 groups)
    if (blockIdx.y == 0) {
        const float4* rw = (const float4*)rel_w;
#pragma unroll
        for (int k = 0; k < 2; k++) {
            const int i = bh * 512 + k * 256 + tid;
            const float4 v = rw[i];
            bf16x4 o;
            o[0] = (__bf16)v.x; o[1] = (__bf16)v.y; o[2] = (__bf16)v.z; o[3] = (__bf16)v.w;
            *(bf16x4*)(relb + i * 4) = o;
        }
    }

    // stage means: f32 -> 3-way bf16 split (swizzled) + row norms^2
    {
        const int r = tid >> 2, qt = tid & 3;        // row 0..63, 16-float seg
        const float4* src = (const float4*)(means + (size_t)(h * NC + r) * DD + qt * 16);
        float4 f[4];
        f[0] = src[0]; f[1] = src[1]; f[2] = src[2]; f[3] = src[3];
        bf16x8 vh[2], vm[2], vl[2];
        float ssq = 0.f;
#pragma unroll
        for (int j = 0; j < 16; j++) {
            const float xx = ((const float*)f)[j];
            ssq = fmaf(xx, xx, ssq);
            const __bf16 hh_ = (__bf16)xx;
            const float r1 = xx - (float)hh_;
            const __bf16 mm_ = (__bf16)r1;
            const float r2 = r1 - (float)mm_;
            vh[j >> 3][j & 7] = hh_; vm[j >> 3][j & 7] = mm_; vl[j >> 3][j & 7] = (__bf16)r2;
        }
#pragma unroll
        for (int gg = 0; gg < 2; gg++) {
            const int dst = QD_ADDR(r, qt * 2 + gg);
            *(bf16x8*)(ah + dst) = vh[gg];
            *(bf16x8*)(am + dst) = vm[gg];
            *(bf16x8*)(al + dst) = vl[gg];
        }
        ssq += __shfl_xor(ssq, 1);
        ssq += __shfl_xor(ssq, 2);
        if (qt == 0) mn2S[r] = ssq;
    }
    // stage qk: split into 3 bf16 tiles + fp32 norms
    {
        const int r = tid >> 2, qt = tid & 3;        // row, 16-float segment
        const float4* src = (const float4*)(qk + ((size_t)bh * TT + t0 + r) * DD + qt * 16);
        float4 f[4];
        f[0] = src[0]; f[1] = src[1]; f[2] = src[2]; f[3] = src[3];
        bf16x8 vh[2], vm[2], vl[2];
        float ssq = 0.f;
#pragma unroll
        for (int j = 0; j < 16; j++) {
            const float xx = ((const float*)f)[j];
            ssq = fmaf(xx, xx, ssq);
            const __bf16 hh_ = (__bf16)xx;
            const float r1 = xx - (float)hh_;
            const __bf16 mm_ = (__bf16)r1;
            const float r2 = r1 - (float)mm_;
            vh[j >> 3][j & 7] = hh_; vm[j >> 3][j & 7] = mm_; vl[j >> 3][j & 7] = (__bf16)r2;
        }
#pragma unroll
        for (int gg = 0; gg < 2; gg++) {
            const int dst = QD_ADDR(r, qt * 2 + gg);
            *(bf16x8*)(qh + dst) = vh[gg];
            *(bf16x8*)(qm + dst) = vm[gg];
            *(bf16x8*)(ql + dst) = vl[gg];
        }
        ssq += __shfl_xor(ssq, 1);
        ssq += __shfl_xor(ssq, 2);
        if (qt == 0) {
            const float inv = 1.0f / fmaxf(sqrtf(ssq), 1e-12f);
            invS[r] = inv;
            s2S[r] = ssq * inv * inv;
        }
    }
    __syncthreads();

    const int lane = tid & 63, wv = tid >> 6;
    const int lo = lane & 15, quad = lane >> 4;

    // B-frags: this wave's token tile (col = lo, k = quad*8 + kh*32)
    bf16x8 Bh[2], Bm[2], Bl[2];
    {
        const int row = wv * 16 + lo;
#pragma unroll
        for (int kh = 0; kh < 2; kh++) {
            const int src = QD_ADDR(row, kh * 4 + quad);
            Bh[kh] = *(const bf16x8*)(qh + src);
            Bm[kh] = *(const bf16x8*)(qm + src);
            Bl[kh] = *(const bf16x8*)(ql + src);
        }
    }

    f32x4 acc[4];
#pragma unroll
    for (int ct = 0; ct < 4; ct++) {
        bf16x8 Ah[2], Am[2], Al[2];
#pragma unroll
        for (int kh = 0; kh < 2; kh++) {
            const int src = QD_ADDR(ct * 16 + lo, kh * 4 + quad);
            Ah[kh] = *(const bf16x8*)(ah + src);
            Am[kh] = *(const bf16x8*)(am + src);
            Al[kh] = *(const bf16x8*)(al + src);
        }
        f32x4 a = (f32x4){0.f, 0.f, 0.f, 0.f};
        // ~2^-24 terms
        a = MFMA(Al[0], Bm[0], a); a = MFMA(Al[1], Bm[1], a);
        a = MFMA(Am[0], Bl[0], a); a = MFMA(Am[1], Bl[1], a);
        // ~2^-16 terms
        a = MFMA(Am[0], Bm[0], a); a = MFMA(Am[1], Bm[1], a);
        a = MFMA(Ah[0], Bl[0], a); a = MFMA(Ah[1], Bl[1], a);
        a = MFMA(Al[0], Bh[0], a); a = MFMA(Al[1], Bh[1], a);
        // ~2^-8 terms
        a = MFMA(Am[0], Bh[0], a); a = MFMA(Am[1], Bh[1], a);
        a = MFMA(Ah[0], Bm[0], a); a = MFMA(Ah[1], Bm[1], a);
        // main term
        a = MFMA(Ah[0], Bh[0], a); a = MFMA(Ah[1], Bh[1], a);
        acc[ct] = a;
    }

    // epilogue: keys + per-token argmax (for loss only)
    const int tok = wv * 16 + lo;
    const float inv = invS[tok];
    float rawmax = -3.0e38f; int cbest = 0;
    u32* kout = keys + (size_t)bh * NC * TT + (size_t)(t0 + tok);
#pragma unroll
    for (int ct = 0; ct < 4; ct++)
#pragma unroll
        for (int r = 0; r < 4; r++) {
            const float raw = acc[ct][r];
            const int c = ct * 16 + quad * 4 + r;
            if (raw > rawmax) { rawmax = raw; cbest = c; }
            kout[(size_t)c * TT] = monokey(raw * inv);
        }

    // merge argmax across quads (lanes lo+16q share token lo)
#pragma unroll
    for (int off = 16; off < 64; off <<= 1) {
        const float ov = __shfl_xor(rawmax, off);
        const int   oc = __shfl_xor(cbest, off);
        if (ov > rawmax || (ov == rawmax && oc < cbest)) { rawmax = ov; cbest = oc; }
    }
    double lt_lane = 0.0;
    if (quad == 0)
        lt_lane = (double)(s2S[tok] + mn2S[cbest] - 2.0f * rawmax * inv);

    // block loss reduction
#pragma unroll
    for (int o = 32; o; o >>= 1) lt_lane += __shfl_xor(lt_lane, o);
    if (lane == 0) red[wv] = lt_lane;
    __syncthreads();
    if (tid == 0) atomicAdd(lossa, red[0] + red[1] + red[2] + red[3]);
}

// ---------------------------------------------------------------------------
// Kernel 2: top-128 per (bh,c), 8-bit radix select on u32 monotone keys.
// ---------------------------------------------------------------------------
__global__ __launch_bounds__(256) void k_topk(
    const u32* __restrict__ keys, int* __restrict__ indices,
    unsigned int* __restrict__ cnt, unsigned short* __restrict__ inv)
{
    __shared__ unsigned int hist[4][256];    // 4 KB
    __shared__ int wsum[8];
    __shared__ int bc_bin, bc_rank, bc_cnt;

    const int bhc = blockIdx.x, tid = threadIdx.x;
    const int wv = tid >> 6, lane = tid & 63;
    const int bh = bhc >> 6;

    u32 key[32];
    {
        const uint4* p = (const uint4*)(keys + (size_t)bhc * TT + tid * 32);
#pragma unroll
        for (int i = 0; i < 8; i++) {
            uint4 u = p[i];
            key[4*i] = u.x; key[4*i+1] = u.y; key[4*i+2] = u.z; key[4*i+3] = u.w;
        }
    }

    u32 thr = 0;
    int need = 128, gshift = 24, prevShift = 0;
    unsigned int* hb = &hist[0][0];

    for (int level = 0; level < 4; level++) {
        const int shift = 24 - 8 * level;
        hb[tid] = 0; hb[tid + 256] = 0; hb[tid + 512] = 0; hb[tid + 768] = 0;
        __syncthreads();
        unsigned int* hw = hist[wv];
        if (level == 0) {
#pragma unroll
            for (int i = 0; i < 32; i++)
                atomicAdd(&hw[key[i] >> 24], 1u);
        } else {
            const u32 pv = thr >> prevShift;
#pragma unroll
            for (int i = 0; i < 32; i++)
                if ((key[i] >> prevShift) == pv)
                    atomicAdd(&hw[(key[i] >> shift) & 255u], 1u);
        }
        __syncthreads();

        const int b = 255 - tid;
        const int c = hist[0][b] + hist[1][b] + hist[2][b] + hist[3][b];
        int incl = c;
#pragma unroll
        for (int o = 1; o < 64; o <<= 1) {
            const int v = __shfl_up(incl, o);
            if (lane >= o) incl += v;
        }
        if (lane == 63) wsum[wv] = incl;
        __syncthreads();
        int above = incl - c;
        for (int wj = 0; wj < wv; wj++) above += wsum[wj];
        if (above < need && above + c >= need) {
            bc_bin = b; bc_rank = above; bc_cnt = c;
        }
        __syncthreads();
        thr |= ((u32)bc_bin) << shift;
        need -= bc_rank;
        gshift = shift;
        prevShift = shift;
        if (bc_cnt == need || shift == 0) break;
    }

    // ordered emission + inverse map
    const u32 tg = thr >> gshift;
    int cgt = 0, ceq = 0;
#pragma unroll
    for (int i = 0; i < 32; i++) {
        const u32 kg = key[i] >> gshift;
        cgt += (kg > tg) ? 1 : 0;
        ceq += (kg == tg) ? 1 : 0;
    }
    int ig = cgt, ie = ceq;
#pragma unroll
    for (int o = 1; o < 64; o <<= 1) {
        const int vg = __shfl_up(ig, o);
        const int ve = __shfl_up(ie, o);
        if (lane >= o) { ig += vg; ie += ve; }
    }
    if (lane == 63) { wsum[wv] = ig; wsum[4 + wv] = ie; }
    __syncthreads();
    int pgt = ig - cgt, peq = ie - ceq;
    for (int wj = 0; wj < wv; wj++) { pgt += wsum[wj]; peq += wsum[4 + wj]; }

    const int rneed = need;
    int* outp = indices + bhc * WW;
    unsigned int* cntb = cnt + (bh << 13);
    unsigned short* invb = inv + (((size_t)bh << 13) * INVCAP);
    const int cbase = (bhc & 63) * WW;
    int g = 0, e = 0;
#pragma unroll
    for (int i = 0; i < 32; i++) {
        const int tok = tid * 32 + i;
        const u32 kg = key[i] >> gshift;
        if (kg > tg) {
            const int tb = (peq + e < rneed) ? (peq + e) : rneed;
            const int wpos = pgt + g + tb;
            outp[wpos] = tok;
            const unsigned int pos = atomicAdd(&cntb[tok], 1u);
            if (pos < INVCAP) invb[(size_t)tok * INVCAP + pos] = (unsigned short)(cbase + wpos);
            g++;
        } else if (kg == tg) {
            if (peq + e < rneed) {
                const int wpos = pgt + g + peq + e;
                outp[wpos] = tok;
                const unsigned int pos = atomicAdd(&cntb[tok], 1u);
                if (pos < INVCAP) invb[(size_t)tok * INVCAP + pos] = (unsigned short)(cbase + wpos);
            }
            e++;
        }
    }
}

// ---------------------------------------------------------------------------
// Kernel 3: per-(bh,c) local attention, MFMA bf16. 512 threads = 8 waves.
// LDS diet: R packed as upper triangle (8256 elems), PV split in two K-halves
// with per-wave P-half buffer (stride 72). Unions {qs->Phalf} + {rp->vt}
// = 36352 B -> 4 blocks/CU when VGPR<=64. NOTE: no min-waves clamp in
// launch_bounds — (512,8) forced VGPR=32 and spilled acc[] to scratch
// (+170MB HBM traffic, R6 regression). Let the allocator breathe.
// ---------------------------------------------------------------------------
#define QS_ADDR(row, gi) (((row) << 6) + ((((gi) ^ ((row) & 7))) << 3))

__global__ __launch_bounds__(512) void k_attn(
    const float* __restrict__ qk, const float* __restrict__ vin,
    const __bf16* __restrict__ relb, const int* __restrict__ indices,
    float* __restrict__ bo)
{
    __shared__ __attribute__((aligned(16))) __bf16 u1[128 * 72];   // qs (swz, stride 64) -> P half (stride 72)
    __shared__ __attribute__((aligned(16))) __bf16 u2[64 * 136];   // rp packed triangle -> v^T (stride 136)
    __shared__ float invs[128];

    const int tid  = threadIdx.x;
    const int lane = tid & 63;
    const int wv   = tid >> 6;
    const int lo   = lane & 15;
    const int quad = lane >> 4;
    const int rbase = wv * 16;

    const int bhc = blockIdx.x;
    const int bh  = bhc >> 6;
    const int h   = bh & 7;

    // ---- q gather, v prefetch in regs (row index straight from global) ----
    const int r  = tid >> 2;          // row 0..127
    const int qp = tid & 3;           // 16-float segment
    const int rowidx = indices[bhc * WW + r];
    const size_t rowoff = ((size_t)bh * TT + rowidx) * DD + qp * 16;
    float4 vreg[4];
    {
        float4 q0, q1, q2, q3;
        const float4* qsrc = (const float4*)(qk + rowoff);
        q0 = qsrc[0]; q1 = qsrc[1]; q2 = qsrc[2]; q3 = qsrc[3];
        const float4* vsrc = (const float4*)(vin + rowoff);
        vreg[0] = vsrc[0]; vreg[1] = vsrc[1]; vreg[2] = vsrc[2]; vreg[3] = vsrc[3];

        float ssq = q0.x*q0.x + q0.y*q0.y + q0.z*q0.z + q0.w*q0.w
                  + q1.x*q1.x + q1.y*q1.y + q1.z*q1.z + q1.w*q1.w
                  + q2.x*q2.x + q2.y*q2.y + q2.z*q2.z + q2.w*q2.w
                  + q3.x*q3.x + q3.y*q3.y + q3.z*q3.z + q3.w*q3.w;
        ssq += __shfl_xor(ssq, 1);
        ssq += __shfl_xor(ssq, 2);
        if (qp == 0) invs[r] = 1.0f / fmaxf(sqrtf(ssq), 1e-12f);
        bf16x8 va, vb;
        va[0]=(__bf16)q0.x; va[1]=(__bf16)q0.y; va[2]=(__bf16)q0.z; va[3]=(__bf16)q0.w;
        va[4]=(__bf16)q1.x; va[5]=(__bf16)q1.y; va[6]=(__bf16)q1.z; va[7]=(__bf16)q1.w;
        vb[0]=(__bf16)q2.x; vb[1]=(__bf16)q2.y; vb[2]=(__bf16)q2.z; vb[3]=(__bf16)q2.w;
        vb[4]=(__bf16)q3.x; vb[5]=(__bf16)q3.y; vb[6]=(__bf16)q3.z; vb[7]=(__bf16)q3.w;
        *(bf16x8*)(u1 + QS_ADDR(r, qp * 2))     = va;
        *(bf16x8*)(u1 + QS_ADDR(r, qp * 2 + 1)) = vb;
    }
    __syncthreads();   // S1: qs + invs complete

    f32x4 acc[8];

    // ---- R = Q * W^T -> packed upper triangle rp[i(i+1)/2 + j] ----
#pragma unroll
    for (int nt = 0; nt < 8; nt++) acc[nt] = (f32x4){0.f, 0.f, 0.f, 0.f};
#pragma unroll
    for (int k0 = 0; k0 < 64; k0 += 32) {
        bf16x8 qa = *(const bf16x8*)(u1 + QS_ADDR(rbase + lo, (k0 >> 3) + quad));
#pragma unroll
        for (int nt = 0; nt < 8; nt++) {
            const bf16x8 wb = *(const bf16x8*)(relb + ((nt * 16 + lo) * 8 + h) * 64 + k0 + quad * 8);
            acc[nt] = MFMA(qa, wb, acc[nt]);
        }
    }
    // element (i, jj=nt*16+lo): bias needs jj >= 127-i -> packed[i(i+1)/2 + (jj-127+i)]
#pragma unroll
    for (int nt = 0; nt < 8; nt++)
#pragma unroll
        for (int rg = 0; rg < 4; rg++) {
            const int i = rbase + quad * 4 + rg;
            const int jsrc = nt * 16 + lo - 127 + i;
            if (jsrc >= 0)
                u2[((i * (i + 1)) >> 1) + jsrc] = (__bf16)acc[nt][rg];
        }

    // ---- dots = (Q*Q^T) * inv_j * scale ----
#pragma unroll
    for (int nt = 0; nt < 8; nt++) acc[nt] = (f32x4){0.f, 0.f, 0.f, 0.f};
#pragma unroll
    for (int k0 = 0; k0 < 64; k0 += 32) {
        bf16x8 qa = *(const bf16x8*)(u1 + QS_ADDR(rbase + lo, (k0 >> 3) + quad));
#pragma unroll
        for (int nt = 0; nt < 8; nt++) {
            bf16x8 qb = *(const bf16x8*)(u1 + QS_ADDR(nt * 16 + lo, (k0 >> 3) + quad));
            acc[nt] = MFMA(qa, qb, acc[nt]);
        }
    }

    // bias (packed triangle read, wave-internal) + self-mask
#pragma unroll
    for (int rg = 0; rg < 4; rg++) {
        const int i = rbase + quad * 4 + rg;
        const int off = (i * (i + 1)) >> 1;
#pragma unroll
        for (int nt = 0; nt < 8; nt++) {
            const int j = nt * 16 + lo;
            float val = acc[nt][rg] * invs[j] * SCALE;
            if (j <= i) val += SCALE * (float)u2[off + j];
            if (j == i) val = -50000.0f;
            acc[nt][rg] = val;
        }
    }

    // row softmax (fully in registers; P stays in acc)
#pragma unroll
    for (int rg = 0; rg < 4; rg++) {
        float m = -3.0e38f;
#pragma unroll
        for (int nt = 0; nt < 8; nt++) m = fmaxf(m, acc[nt][rg]);
#pragma unroll
        for (int msk = 1; msk < 16; msk <<= 1) m = fmaxf(m, __shfl_xor(m, msk));
        float s = 0.f;
#pragma unroll
        for (int nt = 0; nt < 8; nt++) {
            const float e = __expf(acc[nt][rg] - m);
            acc[nt][rg] = e; s += e;
        }
#pragma unroll
        for (int msk = 1; msk < 16; msk <<= 1) s += __shfl_xor(s, msk);
        const float is = 1.0f / s;
#pragma unroll
        for (int nt = 0; nt < 8; nt++) acc[nt][rg] *= is;
    }
    __syncthreads();   // S2: all qs reads (QK) + rp reads (bias) done

    // ---- v (from regs) transposed into u2: vt[d][j], stride 136 ----
    __bf16* vt = u2;
#pragma unroll
    for (int i = 0; i < 4; i++) {
        vt[(qp * 16 + 4*i + 0) * 136 + r] = (__bf16)vreg[i].x;
        vt[(qp * 16 + 4*i + 1) * 136 + r] = (__bf16)vreg[i].y;
        vt[(qp * 16 + 4*i + 2) * 136 + r] = (__bf16)vreg[i].z;
        vt[(qp * 16 + 4*i + 3) * 136 + r] = (__bf16)vreg[i].w;
    }
    // ---- P half 1 (j=0..63) into u1, stride 72 (wave-internal rows) ----
#pragma unroll
    for (int nt = 0; nt < 4; nt++)
#pragma unroll
        for (int rg = 0; rg < 4; rg++)
            u1[(rbase + quad * 4 + rg) * 72 + nt * 16 + lo] = (__bf16)acc[nt][rg];
    __syncthreads();   // S3: vt complete (cross-wave); P half1 in place

    // ---- bo = P * V, K-half 1 (j=0..63) ----
    f32x4 accO[4];
#pragma unroll
    for (int nt = 0; nt < 4; nt++) accO[nt] = (f32x4){0.f, 0.f, 0.f, 0.f};
#pragma unroll
    for (int k0 = 0; k0 < 64; k0 += 32) {
        bf16x8 pa = *(const bf16x8*)(u1 + (rbase + lo) * 72 + k0 + quad * 8);
#pragma unroll
        for (int nt = 0; nt < 4; nt++) {
            bf16x8 vb = *(const bf16x8*)(vt + (nt * 16 + lo) * 136 + k0 + quad * 8);
            accO[nt] = MFMA(pa, vb, accO[nt]);
        }
    }

    // ---- P half 2 (j=64..127) overwrites half 1 (wave-internal) ----
#pragma unroll
    for (int nt = 4; nt < 8; nt++)
#pragma unroll
        for (int rg = 0; rg < 4; rg++)
            u1[(rbase + quad * 4 + rg) * 72 + (nt - 4) * 16 + lo] = (__bf16)acc[nt][rg];

    // ---- bo = P * V, K-half 2 (j=64..127), accumulate ----
#pragma unroll
    for (int k0 = 0; k0 < 64; k0 += 32) {
        bf16x8 pa = *(const bf16x8*)(u1 + (rbase + lo) * 72 + k0 + quad * 8);
#pragma unroll
        for (int nt = 0; nt < 4; nt++) {
            bf16x8 vb = *(const bf16x8*)(vt + (nt * 16 + lo) * 136 + 64 + k0 + quad * 8);
            accO[nt] = MFMA(pa, vb, accO[nt]);
        }
    }

    // ---- dense store ----
    float* bb = bo + (size_t)bhc * (WW * DD);
#pragma unroll
    for (int rg = 0; rg < 4; rg++) {
        const int i = rbase + quad * 4 + rg;
#pragma unroll
        for (int nt = 0; nt < 4; nt++)
            bb[(size_t)i * DD + nt * 16 + lo] = accO[nt][rg];
    }
}

// ---------------------------------------------------------------------------
// Kernel 4: per-token gather-sum of dense bo rows + normalize (+ loss).
// Slots 0..7 prefetched via one 16-B load -> up to 8 INDEPENDENT row gathers
// issue in parallel (was a serial dependent chain). Tail loop only for nc>8.
// ---------------------------------------------------------------------------
__global__ __launch_bounds__(256) void k_out(
    const float* __restrict__ bo, const unsigned int* __restrict__ cnt,
    const unsigned short* __restrict__ inv, const double* __restrict__ lossa,
    float* __restrict__ out)
{
    const int tid = threadIdx.x;
    const int g = blockIdx.x * 16 + (tid >> 4);      // global token 0..262143
    const int l = tid & 15;
    const int bh = g >> 13;
    const unsigned int n = cnt[g];
    const int nc = (n < (unsigned)INVCAP) ? (int)n : INVCAP;
    const unsigned short* ip = inv + (size_t)g * INVCAP;
    const float* bbase = bo + (((size_t)bh << 13) * DD) + l * 4;

    // prefetch first 8 slot ids in one 16-B load (inv rows are 48 B, 16-aligned)
    const uint4 ipv = *(const uint4*)ip;
    const int s0 = ipv.x & 0xffff, s1 = ipv.x >> 16;
    const int s2 = ipv.y & 0xffff, s3 = ipv.y >> 16;
    const int s4 = ipv.z & 0xffff, s5 = ipv.z >> 16;
    const int s6 = ipv.w & 0xffff, s7 = ipv.w >> 16;

    float4 a0 = {0.f,0.f,0.f,0.f}, a1 = a0, a2 = a0, a3 = a0;
    float4 a4 = a0, a5 = a0, a6 = a0, a7 = a0;
    if (nc > 0) a0 = *(const float4*)(bbase + (size_t)s0 * DD);
    if (nc > 1) a1 = *(const float4*)(bbase + (size_t)s1 * DD);
    if (nc > 2) a2 = *(const float4*)(bbase + (size_t)s2 * DD);
    if (nc > 3) a3 = *(const float4*)(bbase + (size_t)s3 * DD);
    if (nc > 4) a4 = *(const float4*)(bbase + (size_t)s4 * DD);
    if (nc > 5) a5 = *(const float4*)(bbase + (size_t)s5 * DD);
    if (nc > 6) a6 = *(const float4*)(bbase + (size_t)s6 * DD);
    if (nc > 7) a7 = *(const float4*)(bbase + (size_t)s7 * DD);

    float4 s;
    s.x = ((a0.x + a1.x) + (a2.x + a3.x)) + ((a4.x + a5.x) + (a6.x + a7.x));
    s.y = ((a0.y + a1.y) + (a2.y + a3.y)) + ((a4.y + a5.y) + (a6.y + a7.y));
    s.z = ((a0.z + a1.z) + (a2.z + a3.z)) + ((a4.z + a5.z) + (a6.z + a7.z));
    s.w = ((a0.w + a1.w) + (a2.w + a3.w)) + ((a4.w + a5.w) + (a6.w + a7.w));

    for (int e = 8; e < nc; e++) {
        const int slot = ip[e];
        const float4 v4 = *(const float4*)(bbase + (size_t)slot * DD);
        s.x += v4.x; s.y += v4.y; s.z += v4.z; s.w += v4.w;
    }

    const float r = 1.0f / ((float)n + 1e-5f);
    s.x *= r; s.y *= r; s.z *= r; s.w *= r;
    *(float4*)(out + (size_t)g * DD + l * 4) = s;
    if (g == 0 && l == 0) out[16777216] = (float)(lossa[0] * (0.0001 / 16777216.0));
}

// ---------------------------------------------------------------------------
extern "C" void kernel_launch(void* const* d_in, const int* in_sizes, int n_in,
                              void* d_out, int out_size, void* d_ws, size_t ws_size,
                              hipStream_t stream) {
    (void)in_sizes; (void)n_in; (void)ws_size; (void)out_size;
    const float* qk    = (const float*)d_in[0];
    const float* v     = (const float*)d_in[1];
    const float* means = (const float*)d_in[2];
    const float* rel_w = (const float*)d_in[3];
    float* out = (float*)d_out;

    // ws layout:
    //   [keys u32 67MB]           (bo 67MB aliases it after k_topk)
    //   [idx 1MB]
    //   [cnt 1MB][lossa pad 4KB]  (memset region)
    //   [inv u16 cap24 12.6MB]
    //   [relb bf16 128KB]
    char* ws = (char*)d_ws;
    const size_t KEYS_B = (size_t)BHN * NC * TT * 4;        // 67108864
    const size_t IDX_B  = (size_t)BHN * NC * WW * 4;        // 1048576
    const size_t CNT_B  = (size_t)BHN * TT * 4;             // 1048576
    const size_t INV_B  = (size_t)BHN * TT * INVCAP * 2;    // 12582912
    u32*            keys  = (u32*)ws;
    float*          bo    = (float*)ws;                     // alias, post-k_topk
    int*            idx   = (int*)(ws + KEYS_B);
    unsigned int*   cnt   = (unsigned int*)(ws + KEYS_B + IDX_B);
    double*         lossa = (double*)(ws + KEYS_B + IDX_B + CNT_B);
    unsigned short* inv   = (unsigned short*)(ws + KEYS_B + IDX_B + CNT_B + 4096);
    __bf16*         relb  = (__bf16*)(ws + KEYS_B + IDX_B + CNT_B + 4096 + INV_B);

    hipMemsetAsync(ws + KEYS_B + IDX_B, 0, CNT_B + 4096, stream);

    k_dists<<<dim3(BHN, TT / DTPB), 256, 0, stream>>>(qk, means, rel_w, relb, keys, lossa);
    k_topk<<<BHN * NC, 256, 0, stream>>>(keys, idx, cnt, inv);
    k_attn<<<BHN * NC, 512, 0, stream>>>(qk, v, relb, idx, bo);
    k_out<<<BHN * TT / 16, 256, 0, stream>>>(bo, cnt, inv, lossa, out);
}

// Round 8
// 326.166 us; speedup vs baseline: 1.1152x; 1.0440x over previous
//
#include <hip/hip_runtime.h>
#include <hip/hip_bf16.h>
#include <math.h>

// Problem constants (b=4,h=8,t=8192,d=64, c=64 clusters, wsz=128)
#define NB 4
#define NH 8
#define TT 8192
#define DD 64
#define NC 64
#define WW 128
#define BHN 32            // NB*NH
#define SCALE 0.125f      // d^-0.5
#define INVCAP 24         // max tracked clusters per token
#define DTPB 64           // tokens per k_dists block

typedef __bf16  bf16x8 __attribute__((ext_vector_type(8)));
typedef __bf16  bf16x4 __attribute__((ext_vector_type(4)));
typedef float   f32x4  __attribute__((ext_vector_type(4)));
typedef unsigned long long u64;
typedef unsigned int u32;

#define MFMA(a, b, c) __builtin_amdgcn_mfma_f32_16x16x32_bf16((a), (b), (c), 0, 0, 0)

// fixed-point monotone key: dv in [-1,1] -> (dv+1)*2^31 (double intermediate,
// res 4.7e-10). Spreads the top radix byte over ~70 bins (cos-sim std ~0.125)
// vs ~6 hot float-exponent bins for raw-float monokey -> ~10x fewer LDS-atomic
// serialization stalls in k_topk's level-0 histogram.
__device__ __forceinline__ u32 fixkey32(float dv) {
    double k = ((double)dv + 1.0) * 2147483648.0;
    k = fmin(fmax(k, 0.0), 4294967295.0);
    return (u32)k;
}

// ---------------------------------------------------------------------------
// Kernel 1: routing dists via error-compensated bf16 MFMA -> fixed-point u32
// keys (+ loss). Block: 64 tokens x 64 clusters, 4 waves (1 token-tile each).
// Means split f32->3xbf16 INLINE; by==0 blocks also pre-cast rel_w -> bf16.
// ---------------------------------------------------------------------------
#define QD_ADDR(row, gi) (((row) << 6) + ((((gi) ^ ((row) & 7))) << 3))

__global__ __launch_bounds__(256) void k_dists(
    const float* __restrict__ qk, const float* __restrict__ means,
    const float* __restrict__ rel_w, __bf16* __restrict__ relb,
    u32* __restrict__ keys, double* __restrict__ lossa)
{
    __shared__ __attribute__((aligned(16))) __bf16 qh[64 * 64], qm[64 * 64], ql[64 * 64];
    __shared__ __attribute__((aligned(16))) __bf16 ah[64 * 64], am[64 * 64], al[64 * 64];
    __shared__ float invS[DTPB], s2S[DTPB], mn2S[NC];
    __shared__ double red[4];

    const int bh = blockIdx.x, h = bh & 7, tid = threadIdx.x;
    const int t0 = blockIdx.y * DTPB;

    // rel_w -> bf16 cast (32 by==0 blocks cover 16384 float4 groups)
    if (blockIdx.y == 0) {
        const float4* rw = (const float4*)rel_w;
#pragma unroll
        for (int k = 0; k < 2; k++) {
            const int i = bh * 512 + k * 256 + tid;
            const float4 v = rw[i];
            bf16x4 o;
            o[0] = (__bf16)v.x; o[1] = (__bf16)v.y; o[2] = (__bf16)v.z; o[3] = (__bf16)v.w;
            *(bf16x4*)(relb + i * 4) = o;
        }
    }

    // stage means: f32 -> 3-way bf16 split (swizzled) + row norms^2
    {
        const int r = tid >> 2, qt = tid & 3;        // row 0..63, 16-float seg
        const float4* src = (const float4*)(means + (size_t)(h * NC + r) * DD + qt * 16);
        float4 f[4];
        f[0] = src[0]; f[1] = src[1]; f[2] = src[2]; f[3] = src[3];
        bf16x8 vh[2], vm[2], vl[2];
        float ssq = 0.f;
#pragma unroll
        for (int j = 0; j < 16; j++) {
            const float xx = ((const float*)f)[j];
            ssq = fmaf(xx, xx, ssq);
            const __bf16 hh_ = (__bf16)xx;
            const float r1 = xx - (float)hh_;
            const __bf16 mm_ = (__bf16)r1;
            const float r2 = r1 - (float)mm_;
            vh[j >> 3][j & 7] = hh_; vm[j >> 3][j & 7] = mm_; vl[j >> 3][j & 7] = (__bf16)r2;
        }
#pragma unroll
        for (int gg = 0; gg < 2; gg++) {
            const int dst = QD_ADDR(r, qt * 2 + gg);
            *(bf16x8*)(ah + dst) = vh[gg];
            *(bf16x8*)(am + dst) = vm[gg];
            *(bf16x8*)(al + dst) = vl[gg];
        }
        ssq += __shfl_xor(ssq, 1);
        ssq += __shfl_xor(ssq, 2);
        if (qt == 0) mn2S[r] = ssq;
    }
    // stage qk: split into 3 bf16 tiles + fp32 norms
    {
        const int r = tid >> 2, qt = tid & 3;        // row, 16-float segment
        const float4* src = (const float4*)(qk + ((size_t)bh * TT + t0 + r) * DD + qt * 16);
        float4 f[4];
        f[0] = src[0]; f[1] = src[1]; f[2] = src[2]; f[3] = src[3];
        bf16x8 vh[2], vm[2], vl[2];
        float ssq = 0.f;
#pragma unroll
        for (int j = 0; j < 16; j++) {
            const float xx = ((const float*)f)[j];
            ssq = fmaf(xx, xx, ssq);
            const __bf16 hh_ = (__bf16)xx;
            const float r1 = xx - (float)hh_;
            const __bf16 mm_ = (__bf16)r1;
            const float r2 = r1 - (float)mm_;
            vh[j >> 3][j & 7] = hh_; vm[j >> 3][j & 7] = mm_; vl[j >> 3][j & 7] = (__bf16)r2;
        }
#pragma unroll
        for (int gg = 0; gg < 2; gg++) {
            const int dst = QD_ADDR(r, qt * 2 + gg);
            *(bf16x8*)(qh + dst) = vh[gg];
            *(bf16x8*)(qm + dst) = vm[gg];
            *(bf16x8*)(ql + dst) = vl[gg];
        }
        ssq += __shfl_xor(ssq, 1);
        ssq += __shfl_xor(ssq, 2);
        if (qt == 0) {
            const float inv = 1.0f / fmaxf(sqrtf(ssq), 1e-12f);
            invS[r] = inv;
            s2S[r] = ssq * inv * inv;
        }
    }
    __syncthreads();

    const int lane = tid & 63, wv = tid >> 6;
    const int lo = lane & 15, quad = lane >> 4;

    // B-frags: this wave's token tile (col = lo, k = quad*8 + kh*32)
    bf16x8 Bh[2], Bm[2], Bl[2];
    {
        const int row = wv * 16 + lo;
#pragma unroll
        for (int kh = 0; kh < 2; kh++) {
            const int src = QD_ADDR(row, kh * 4 + quad);
            Bh[kh] = *(const bf16x8*)(qh + src);
            Bm[kh] = *(const bf16x8*)(qm + src);
            Bl[kh] = *(const bf16x8*)(ql + src);
        }
    }

    f32x4 acc[4];
#pragma unroll
    for (int ct = 0; ct < 4; ct++) {
        bf16x8 Ah[2], Am[2], Al[2];
#pragma unroll
        for (int kh = 0; kh < 2; kh++) {
            const int src = QD_ADDR(ct * 16 + lo, kh * 4 + quad);
            Ah[kh] = *(const bf16x8*)(ah + src);
            Am[kh] = *(const bf16x8*)(am + src);
            Al[kh] = *(const bf16x8*)(al + src);
        }
        f32x4 a = (f32x4){0.f, 0.f, 0.f, 0.f};
        // ~2^-24 terms
        a = MFMA(Al[0], Bm[0], a); a = MFMA(Al[1], Bm[1], a);
        a = MFMA(Am[0], Bl[0], a); a = MFMA(Am[1], Bl[1], a);
        // ~2^-16 terms
        a = MFMA(Am[0], Bm[0], a); a = MFMA(Am[1], Bm[1], a);
        a = MFMA(Ah[0], Bl[0], a); a = MFMA(Ah[1], Bl[1], a);
        a = MFMA(Al[0], Bh[0], a); a = MFMA(Al[1], Bh[1], a);
        // ~2^-8 terms
        a = MFMA(Am[0], Bh[0], a); a = MFMA(Am[1], Bh[1], a);
        a = MFMA(Ah[0], Bm[0], a); a = MFMA(Ah[1], Bm[1], a);
        // main term
        a = MFMA(Ah[0], Bh[0], a); a = MFMA(Ah[1], Bh[1], a);
        acc[ct] = a;
    }

    // epilogue: keys + per-token argmax (for loss only)
    const int tok = wv * 16 + lo;
    const float inv = invS[tok];
    float rawmax = -3.0e38f; int cbest = 0;
    u32* kout = keys + (size_t)bh * NC * TT + (size_t)(t0 + tok);
#pragma unroll
    for (int ct = 0; ct < 4; ct++)
#pragma unroll
        for (int r = 0; r < 4; r++) {
            const float raw = acc[ct][r];
            const int c = ct * 16 + quad * 4 + r;
            if (raw > rawmax) { rawmax = raw; cbest = c; }
            kout[(size_t)c * TT] = fixkey32(raw * inv);
        }

    // merge argmax across quads (lanes lo+16q share token lo)
#pragma unroll
    for (int off = 16; off < 64; off <<= 1) {
        const float ov = __shfl_xor(rawmax, off);
        const int   oc = __shfl_xor(cbest, off);
        if (ov > rawmax || (ov == rawmax && oc < cbest)) { rawmax = ov; cbest = oc; }
    }
    double lt_lane = 0.0;
    if (quad == 0)
        lt_lane = (double)(s2S[tok] + mn2S[cbest] - 2.0f * rawmax * inv);

    // block loss reduction
#pragma unroll
    for (int o = 32; o; o >>= 1) lt_lane += __shfl_xor(lt_lane, o);
    if (lane == 0) red[wv] = lt_lane;
    __syncthreads();
    if (tid == 0) atomicAdd(lossa, red[0] + red[1] + red[2] + red[3]);
}

// ---------------------------------------------------------------------------
// Kernel 2: top-128 per (bh,c), 8-bit radix select on u32 fixed-point keys.
// ---------------------------------------------------------------------------
__global__ __launch_bounds__(256) void k_topk(
    const u32* __restrict__ keys, int* __restrict__ indices,
    unsigned int* __restrict__ cnt, unsigned short* __restrict__ inv)
{
    __shared__ unsigned int hist[4][256];    // 4 KB
    __shared__ int wsum[8];
    __shared__ int bc_bin, bc_rank, bc_cnt;

    const int bhc = blockIdx.x, tid = threadIdx.x;
    const int wv = tid >> 6, lane = tid & 63;
    const int bh = bhc >> 6;

    u32 key[32];
    {
        const uint4* p = (const uint4*)(keys + (size_t)bhc * TT + tid * 32);
#pragma unroll
        for (int i = 0; i < 8; i++) {
            uint4 u = p[i];
            key[4*i] = u.x; key[4*i+1] = u.y; key[4*i+2] = u.z; key[4*i+3] = u.w;
        }
    }

    u32 thr = 0;
    int need = 128, gshift = 24, prevShift = 0;
    unsigned int* hb = &hist[0][0];

    for (int level = 0; level < 4; level++) {
        const int shift = 24 - 8 * level;
        hb[tid] = 0; hb[tid + 256] = 0; hb[tid + 512] = 0; hb[tid + 768] = 0;
        __syncthreads();
        unsigned int* hw = hist[wv];
        if (level == 0) {
#pragma unroll
            for (int i = 0; i < 32; i++)
                atomicAdd(&hw[key[i] >> 24], 1u);
        } else {
            const u32 pv = thr >> prevShift;
#pragma unroll
            for (int i = 0; i < 32; i++)
                if ((key[i] >> prevShift) == pv)
                    atomicAdd(&hw[(key[i] >> shift) & 255u], 1u);
        }
        __syncthreads();

        const int b = 255 - tid;
        const int c = hist[0][b] + hist[1][b] + hist[2][b] + hist[3][b];
        int incl = c;
#pragma unroll
        for (int o = 1; o < 64; o <<= 1) {
            const int v = __shfl_up(incl, o);
            if (lane >= o) incl += v;
        }
        if (lane == 63) wsum[wv] = incl;
        __syncthreads();
        int above = incl - c;
        for (int wj = 0; wj < wv; wj++) above += wsum[wj];
        if (above < need && above + c >= need) {
            bc_bin = b; bc_rank = above; bc_cnt = c;
        }
        __syncthreads();
        thr |= ((u32)bc_bin) << shift;
        need -= bc_rank;
        gshift = shift;
        prevShift = shift;
        if (bc_cnt == need || shift == 0) break;
    }

    // ordered emission + inverse map
    const u32 tg = thr >> gshift;
    int cgt = 0, ceq = 0;
#pragma unroll
    for (int i = 0; i < 32; i++) {
        const u32 kg = key[i] >> gshift;
        cgt += (kg > tg) ? 1 : 0;
        ceq += (kg == tg) ? 1 : 0;
    }
    int ig = cgt, ie = ceq;
#pragma unroll
    for (int o = 1; o < 64; o <<= 1) {
        const int vg = __shfl_up(ig, o);
        const int ve = __shfl_up(ie, o);
        if (lane >= o) { ig += vg; ie += ve; }
    }
    if (lane == 63) { wsum[wv] = ig; wsum[4 + wv] = ie; }
    __syncthreads();
    int pgt = ig - cgt, peq = ie - ceq;
    for (int wj = 0; wj < wv; wj++) { pgt += wsum[wj]; peq += wsum[4 + wj]; }

    const int rneed = need;
    int* outp = indices + bhc * WW;
    unsigned int* cntb = cnt + (bh << 13);
    unsigned short* invb = inv + (((size_t)bh << 13) * INVCAP);
    const int cbase = (bhc & 63) * WW;
    int g = 0, e = 0;
#pragma unroll
    for (int i = 0; i < 32; i++) {
        const int tok = tid * 32 + i;
        const u32 kg = key[i] >> gshift;
        if (kg > tg) {
            const int tb = (peq + e < rneed) ? (peq + e) : rneed;
            const int wpos = pgt + g + tb;
            outp[wpos] = tok;
            const unsigned int pos = atomicAdd(&cntb[tok], 1u);
            if (pos < INVCAP) invb[(size_t)tok * INVCAP + pos] = (unsigned short)(cbase + wpos);
            g++;
        } else if (kg == tg) {
            if (peq + e < rneed) {
                const int wpos = pgt + g + peq + e;
                outp[wpos] = tok;
                const unsigned int pos = atomicAdd(&cntb[tok], 1u);
                if (pos < INVCAP) invb[(size_t)tok * INVCAP + pos] = (unsigned short)(cbase + wpos);
            }
            e++;
        }
    }
}

// ---------------------------------------------------------------------------
// Kernel 3: per-(bh,c) local attention, MFMA bf16. 512 threads = 8 waves.
// LDS 52736 B -> 3 blocks/CU. qs XOR-swizzled 128x64 (union'd with vt).
// (R4 form: best measured 78us. The 36KB LDS-diet variant did NOT raise
//  occupancy and ran 4% slower — k_attn is not occupancy-bound.)
// ---------------------------------------------------------------------------
#define QS_ADDR(row, gi) (((row) << 6) + ((((gi) ^ ((row) & 7))) << 3))

__global__ __launch_bounds__(512) void k_attn(
    const float* __restrict__ qk, const float* __restrict__ vin,
    const __bf16* __restrict__ relb, const int* __restrict__ indices,
    float* __restrict__ bo)
{
    __shared__ __attribute__((aligned(16))) __bf16 uv[64 * 136];   // qs / later v^T
    __shared__ __attribute__((aligned(16))) __bf16 rs[128 * 136];  // R; later P
    __shared__ float invs[128];

    const int tid  = threadIdx.x;
    const int lane = tid & 63;
    const int wv   = tid >> 6;
    const int lo   = lane & 15;
    const int quad = lane >> 4;
    const int rbase = wv * 16;

    const int bhc = blockIdx.x;
    const int bh  = bhc >> 6;
    const int h   = bh & 7;

    // ---- q gather, v prefetch in regs (row index straight from global) ----
    const int r  = tid >> 2;          // row 0..127
    const int qp = tid & 3;           // 16-float segment
    const int rowidx = indices[bhc * WW + r];
    const size_t rowoff = ((size_t)bh * TT + rowidx) * DD + qp * 16;
    float4 q0, q1, q2, q3, vreg[4];
    {
        const float4* qsrc = (const float4*)(qk + rowoff);
        q0 = qsrc[0]; q1 = qsrc[1]; q2 = qsrc[2]; q3 = qsrc[3];
        const float4* vsrc = (const float4*)(vin + rowoff);
        vreg[0] = vsrc[0]; vreg[1] = vsrc[1]; vreg[2] = vsrc[2]; vreg[3] = vsrc[3];
    }
    {
        float ssq = q0.x*q0.x + q0.y*q0.y + q0.z*q0.z + q0.w*q0.w
                  + q1.x*q1.x + q1.y*q1.y + q1.z*q1.z + q1.w*q1.w
                  + q2.x*q2.x + q2.y*q2.y + q2.z*q2.z + q2.w*q2.w
                  + q3.x*q3.x + q3.y*q3.y + q3.z*q3.z + q3.w*q3.w;
        ssq += __shfl_xor(ssq, 1);
        ssq += __shfl_xor(ssq, 2);
        if (qp == 0) invs[r] = 1.0f / fmaxf(sqrtf(ssq), 1e-12f);
        bf16x8 va, vb;
        va[0]=(__bf16)q0.x; va[1]=(__bf16)q0.y; va[2]=(__bf16)q0.z; va[3]=(__bf16)q0.w;
        va[4]=(__bf16)q1.x; va[5]=(__bf16)q1.y; va[6]=(__bf16)q1.z; va[7]=(__bf16)q1.w;
        vb[0]=(__bf16)q2.x; vb[1]=(__bf16)q2.y; vb[2]=(__bf16)q2.z; vb[3]=(__bf16)q2.w;
        vb[4]=(__bf16)q3.x; vb[5]=(__bf16)q3.y; vb[6]=(__bf16)q3.z; vb[7]=(__bf16)q3.w;
        *(bf16x8*)(uv + QS_ADDR(r, qp * 2))     = va;
        *(bf16x8*)(uv + QS_ADDR(r, qp * 2 + 1)) = vb;
    }
    __syncthreads();

    f32x4 acc[8];

    // ---- R = Q * W^T (W pre-cast bf16, direct 16B loads) ----
#pragma unroll
    for (int nt = 0; nt < 8; nt++) acc[nt] = (f32x4){0.f, 0.f, 0.f, 0.f};
#pragma unroll
    for (int k0 = 0; k0 < 64; k0 += 32) {
        bf16x8 qa = *(const bf16x8*)(uv + QS_ADDR(rbase + lo, (k0 >> 3) + quad));
#pragma unroll
        for (int nt = 0; nt < 8; nt++) {
            const bf16x8 wb = *(const bf16x8*)(relb + ((nt * 16 + lo) * 8 + h) * 64 + k0 + quad * 8);
            acc[nt] = MFMA(qa, wb, acc[nt]);
        }
    }
#pragma unroll
    for (int nt = 0; nt < 8; nt++)
#pragma unroll
        for (int rg = 0; rg < 4; rg++)
            rs[(rbase + quad * 4 + rg) * 136 + nt * 16 + lo] = (__bf16)acc[nt][rg];

    // ---- dots = (Q*Q^T) * inv_j * scale ----
#pragma unroll
    for (int nt = 0; nt < 8; nt++) acc[nt] = (f32x4){0.f, 0.f, 0.f, 0.f};
#pragma unroll
    for (int k0 = 0; k0 < 64; k0 += 32) {
        bf16x8 qa = *(const bf16x8*)(uv + QS_ADDR(rbase + lo, (k0 >> 3) + quad));
#pragma unroll
        for (int nt = 0; nt < 8; nt++) {
            bf16x8 qb = *(const bf16x8*)(uv + QS_ADDR(nt * 16 + lo, (k0 >> 3) + quad));
            acc[nt] = MFMA(qa, qb, acc[nt]);
        }
    }

    float inv_j[8];
#pragma unroll
    for (int nt = 0; nt < 8; nt++) inv_j[nt] = invs[nt * 16 + lo];

    // bias (shifted rel) + self-mask
#pragma unroll
    for (int rg = 0; rg < 4; rg++) {
        const int i = rbase + quad * 4 + rg;
#pragma unroll
        for (int nt = 0; nt < 8; nt++) {
            const int j = nt * 16 + lo;
            float val = acc[nt][rg] * inv_j[nt] * SCALE;
            if (j <= i) val += SCALE * (float)rs[i * 136 + (j + 127 - i)];
            if (j == i) val = -50000.0f;
            acc[nt][rg] = val;
        }
    }

    // row softmax
#pragma unroll
    for (int rg = 0; rg < 4; rg++) {
        float m = -3.0e38f;
#pragma unroll
        for (int nt = 0; nt < 8; nt++) m = fmaxf(m, acc[nt][rg]);
#pragma unroll
        for (int msk = 1; msk < 16; msk <<= 1) m = fmaxf(m, __shfl_xor(m, msk));
        float s = 0.f;
#pragma unroll
        for (int nt = 0; nt < 8; nt++) {
            const float e = __expf(acc[nt][rg] - m);
            acc[nt][rg] = e; s += e;
        }
#pragma unroll
        for (int msk = 1; msk < 16; msk <<= 1) s += __shfl_xor(s, msk);
        const float is = 1.0f / s;
        const int i = rbase + quad * 4 + rg;
#pragma unroll
        for (int nt = 0; nt < 8; nt++)
            rs[i * 136 + nt * 16 + lo] = (__bf16)(acc[nt][rg] * is);
    }
    __syncthreads();   // all reads of uv(q) done; P complete

    // ---- v (from regs) transposed into uv: vt[d][j], stride 136 ----
    __bf16* vt = uv;
#pragma unroll
    for (int i = 0; i < 4; i++) {
        vt[(qp * 16 + 4*i + 0) * 136 + r] = (__bf16)vreg[i].x;
        vt[(qp * 16 + 4*i + 1) * 136 + r] = (__bf16)vreg[i].y;
        vt[(qp * 16 + 4*i + 2) * 136 + r] = (__bf16)vreg[i].z;
        vt[(qp * 16 + 4*i + 3) * 136 + r] = (__bf16)vreg[i].w;
    }
    __syncthreads();

    // ---- bo = P * V ----
    f32x4 accO[4];
#pragma unroll
    for (int nt = 0; nt < 4; nt++) accO[nt] = (f32x4){0.f, 0.f, 0.f, 0.f};
#pragma unroll
    for (int k0 = 0; k0 < 128; k0 += 32) {
        bf16x8 pa = *(const bf16x8*)(rs + (rbase + lo) * 136 + k0 + quad * 8);
#pragma unroll
        for (int nt = 0; nt < 4; nt++) {
            bf16x8 vb = *(const bf16x8*)(vt + (nt * 16 + lo) * 136 + k0 + quad * 8);
            accO[nt] = MFMA(pa, vb, accO[nt]);
        }
    }

    // ---- dense store ----
    float* bb = bo + (size_t)bhc * (WW * DD);
#pragma unroll
    for (int rg = 0; rg < 4; rg++) {
        const int i = rbase + quad * 4 + rg;
#pragma unroll
        for (int nt = 0; nt < 4; nt++)
            bb[(size_t)i * DD + nt * 16 + lo] = accO[nt][rg];
    }
}

// ---------------------------------------------------------------------------
// Kernel 4: per-token gather-sum of dense bo rows + normalize (+ loss).
// Slots 0..7 prefetched via one 16-B load -> up to 8 INDEPENDENT row gathers
// issue in parallel (was a serial dependent chain). Tail loop only for nc>8.
// ---------------------------------------------------------------------------
__global__ __launch_bounds__(256) void k_out(
    const float* __restrict__ bo, const unsigned int* __restrict__ cnt,
    const unsigned short* __restrict__ inv, const double* __restrict__ lossa,
    float* __restrict__ out)
{
    const int tid = threadIdx.x;
    const int g = blockIdx.x * 16 + (tid >> 4);      // global token 0..262143
    const int l = tid & 15;
    const int bh = g >> 13;
    const unsigned int n = cnt[g];
    const int nc = (n < (unsigned)INVCAP) ? (int)n : INVCAP;
    const unsigned short* ip = inv + (size_t)g * INVCAP;
    const float* bbase = bo + (((size_t)bh << 13) * DD) + l * 4;

    // prefetch first 8 slot ids in one 16-B load (inv rows are 48 B, 16-aligned)
    const uint4 ipv = *(const uint4*)ip;
    const int s0 = ipv.x & 0xffff, s1 = ipv.x >> 16;
    const int s2 = ipv.y & 0xffff, s3 = ipv.y >> 16;
    const int s4 = ipv.z & 0xffff, s5 = ipv.z >> 16;
    const int s6 = ipv.w & 0xffff, s7 = ipv.w >> 16;

    float4 a0 = {0.f,0.f,0.f,0.f}, a1 = a0, a2 = a0, a3 = a0;
    float4 a4 = a0, a5 = a0, a6 = a0, a7 = a0;
    if (nc > 0) a0 = *(const float4*)(bbase + (size_t)s0 * DD);
    if (nc > 1) a1 = *(const float4*)(bbase + (size_t)s1 * DD);
    if (nc > 2) a2 = *(const float4*)(bbase + (size_t)s2 * DD);
    if (nc > 3) a3 = *(const float4*)(bbase + (size_t)s3 * DD);
    if (nc > 4) a4 = *(const float4*)(bbase + (size_t)s4 * DD);
    if (nc > 5) a5 = *(const float4*)(bbase + (size_t)s5 * DD);
    if (nc > 6) a6 = *(const float4*)(bbase + (size_t)s6 * DD);
    if (nc > 7) a7 = *(const float4*)(bbase + (size_t)s7 * DD);

    float4 s;
    s.x = ((a0.x + a1.x) + (a2.x + a3.x)) + ((a4.x + a5.x) + (a6.x + a7.x));
    s.y = ((a0.y + a1.y) + (a2.y + a3.y)) + ((a4.y + a5.y) + (a6.y + a7.y));
    s.z = ((a0.z + a1.z) + (a2.z + a3.z)) + ((a4.z + a5.z) + (a6.z + a7.z));
    s.w = ((a0.w + a1.w) + (a2.w + a3.w)) + ((a4.w + a5.w) + (a6.w + a7.w));

    for (int e = 8; e < nc; e++) {
        const int slot = ip[e];
        const float4 v4 = *(const float4*)(bbase + (size_t)slot * DD);
        s.x += v4.x; s.y += v4.y; s.z += v4.z; s.w += v4.w;
    }

    const float r = 1.0f / ((float)n + 1e-5f);
    s.x *= r; s.y *= r; s.z *= r; s.w *= r;
    *(float4*)(out + (size_t)g * DD + l * 4) = s;
    if (g == 0 && l == 0) out[16777216] = (float)(lossa[0] * (0.0001 / 16777216.0));
}

// ---------------------------------------------------------------------------
extern "C" void kernel_launch(void* const* d_in, const int* in_sizes, int n_in,
                              void* d_out, int out_size, void* d_ws, size_t ws_size,
                              hipStream_t stream) {
    (void)in_sizes; (void)n_in; (void)ws_size; (void)out_size;
    const float* qk    = (const float*)d_in[0];
    const float* v     = (const float*)d_in[1];
    const float* means = (const float*)d_in[2];
    const float* rel_w = (const float*)d_in[3];
    float* out = (float*)d_out;

    // ws layout:
    //   [keys u32 67MB]           (bo 67MB aliases it after k_topk)
    //   [idx 1MB]
    //   [cnt 1MB][lossa pad 4KB]  (memset region)
    //   [inv u16 cap24 12.6MB]
    //   [relb bf16 128KB]
    char* ws = (char*)d_ws;
    const size_t KEYS_B = (size_t)BHN * NC * TT * 4;        // 67108864
    const size_t IDX_B  = (size_t)BHN * NC * WW * 4;        // 1048576
    const size_t CNT_B  = (size_t)BHN * TT * 4;             // 1048576
    const size_t INV_B  = (size_t)BHN * TT * INVCAP * 2;    // 12582912
    u32*            keys  = (u32*)ws;
    float*          bo    = (float*)ws;                     // alias, post-k_topk
    int*            idx   = (int*)(ws + KEYS_B);
    unsigned int*   cnt   = (unsigned int*)(ws + KEYS_B + IDX_B);
    double*         lossa = (double*)(ws + KEYS_B + IDX_B + CNT_B);
    unsigned short* inv   = (unsigned short*)(ws + KEYS_B + IDX_B + CNT_B + 4096);
    __bf16*         relb  = (__bf16*)(ws + KEYS_B + IDX_B + CNT_B + 4096 + INV_B);

    hipMemsetAsync(ws + KEYS_B + IDX_B, 0, CNT_B + 4096, stream);

    k_dists<<<dim3(BHN, TT / DTPB), 256, 0, stream>>>(qk, means, rel_w, relb, keys, lossa);
    k_topk<<<BHN * NC, 256, 0, stream>>>(keys, idx, cnt, inv);
    k_attn<<<BHN * NC, 512, 0, stream>>>(qk, v, relb, idx, bo);
    k_out<<<BHN * TT / 16, 256, 0, stream>>>(bo, cnt, inv, lossa, out);
}

// Round 9
// 324.901 us; speedup vs baseline: 1.1195x; 1.0039x over previous
//
#include <hip/hip_runtime.h>
#include <hip/hip_bf16.h>
#include <math.h>

// Problem constants (b=4,h=8,t=8192,d=64, c=64 clusters, wsz=128)
#define NB 4
#define NH 8
#define TT 8192
#define DD 64
#define NC 64
#define WW 128
#define BHN 32            // NB*NH
#define SCALE 0.125f      // d^-0.5
#define INVCAP 24         // max tracked clusters per token
#define DTPB 64           // tokens per k_dists block
#define NTILE 4           // (bh,c) tiles per k_attn block

typedef __bf16  bf16x8 __attribute__((ext_vector_type(8)));
typedef __bf16  bf16x4 __attribute__((ext_vector_type(4)));
typedef float   f32x4  __attribute__((ext_vector_type(4)));
typedef unsigned long long u64;
typedef unsigned int u32;

#define MFMA(a, b, c) __builtin_amdgcn_mfma_f32_16x16x32_bf16((a), (b), (c), 0, 0, 0)

// fixed-point monotone key: dv in [-1,1] -> (dv+1)*2^31 (double intermediate,
// res 4.7e-10). Spreads the top radix byte over ~70 bins vs ~6 float-exponent
// bins -> ~10x fewer LDS-atomic serialization stalls in k_topk level-0.
__device__ __forceinline__ u32 fixkey32(float dv) {
    double k = ((double)dv + 1.0) * 2147483648.0;
    k = fmin(fmax(k, 0.0), 4294967295.0);
    return (u32)k;
}

// ---------------------------------------------------------------------------
// Kernel 1: routing dists via error-compensated bf16 MFMA -> fixed-point u32
// keys (+ loss). Block: 64 tokens x 64 clusters, 4 waves (1 token-tile each).
// Means split f32->3xbf16 INLINE; by==0 blocks also pre-cast rel_w -> bf16.
// ---------------------------------------------------------------------------
#define QD_ADDR(row, gi) (((row) << 6) + ((((gi) ^ ((row) & 7))) << 3))

__global__ __launch_bounds__(256) void k_dists(
    const float* __restrict__ qk, const float* __restrict__ means,
    const float* __restrict__ rel_w, __bf16* __restrict__ relb,
    u32* __restrict__ keys, double* __restrict__ lossa)
{
    __shared__ __attribute__((aligned(16))) __bf16 qh[64 * 64], qm[64 * 64], ql[64 * 64];
    __shared__ __attribute__((aligned(16))) __bf16 ah[64 * 64], am[64 * 64], al[64 * 64];
    __shared__ float invS[DTPB], s2S[DTPB], mn2S[NC];
    __shared__ double red[4];

    const int bh = blockIdx.x, h = bh & 7, tid = threadIdx.x;
    const int t0 = blockIdx.y * DTPB;

    // rel_w -> bf16 cast (32 by==0 blocks cover 16384 float4 groups)
    if (blockIdx.y == 0) {
        const float4* rw = (const float4*)rel_w;
#pragma unroll
        for (int k = 0; k < 2; k++) {
            const int i = bh * 512 + k * 256 + tid;
            const float4 v = rw[i];
            bf16x4 o;
            o[0] = (__bf16)v.x; o[1] = (__bf16)v.y; o[2] = (__bf16)v.z; o[3] = (__bf16)v.w;
            *(bf16x4*)(relb + i * 4) = o;
        }
    }

    // stage means: f32 -> 3-way bf16 split (swizzled) + row norms^2
    {
        const int r = tid >> 2, qt = tid & 3;        // row 0..63, 16-float seg
        const float4* src = (const float4*)(means + (size_t)(h * NC + r) * DD + qt * 16);
        float4 f[4];
        f[0] = src[0]; f[1] = src[1]; f[2] = src[2]; f[3] = src[3];
        bf16x8 vh[2], vm[2], vl[2];
        float ssq = 0.f;
#pragma unroll
        for (int j = 0; j < 16; j++) {
            const float xx = ((const float*)f)[j];
            ssq = fmaf(xx, xx, ssq);
            const __bf16 hh_ = (__bf16)xx;
            const float r1 = xx - (float)hh_;
            const __bf16 mm_ = (__bf16)r1;
            const float r2 = r1 - (float)mm_;
            vh[j >> 3][j & 7] = hh_; vm[j >> 3][j & 7] = mm_; vl[j >> 3][j & 7] = (__bf16)r2;
        }
#pragma unroll
        for (int gg = 0; gg < 2; gg++) {
            const int dst = QD_ADDR(r, qt * 2 + gg);
            *(bf16x8*)(ah + dst) = vh[gg];
            *(bf16x8*)(am + dst) = vm[gg];
            *(bf16x8*)(al + dst) = vl[gg];
        }
        ssq += __shfl_xor(ssq, 1);
        ssq += __shfl_xor(ssq, 2);
        if (qt == 0) mn2S[r] = ssq;
    }
    // stage qk: split into 3 bf16 tiles + fp32 norms
    {
        const int r = tid >> 2, qt = tid & 3;        // row, 16-float segment
        const float4* src = (const float4*)(qk + ((size_t)bh * TT + t0 + r) * DD + qt * 16);
        float4 f[4];
        f[0] = src[0]; f[1] = src[1]; f[2] = src[2]; f[3] = src[3];
        bf16x8 vh[2], vm[2], vl[2];
        float ssq = 0.f;
#pragma unroll
        for (int j = 0; j < 16; j++) {
            const float xx = ((const float*)f)[j];
            ssq = fmaf(xx, xx, ssq);
            const __bf16 hh_ = (__bf16)xx;
            const float r1 = xx - (float)hh_;
            const __bf16 mm_ = (__bf16)r1;
            const float r2 = r1 - (float)mm_;
            vh[j >> 3][j & 7] = hh_; vm[j >> 3][j & 7] = mm_; vl[j >> 3][j & 7] = (__bf16)r2;
        }
#pragma unroll
        for (int gg = 0; gg < 2; gg++) {
            const int dst = QD_ADDR(r, qt * 2 + gg);
            *(bf16x8*)(qh + dst) = vh[gg];
            *(bf16x8*)(qm + dst) = vm[gg];
            *(bf16x8*)(ql + dst) = vl[gg];
        }
        ssq += __shfl_xor(ssq, 1);
        ssq += __shfl_xor(ssq, 2);
        if (qt == 0) {
            const float inv = 1.0f / fmaxf(sqrtf(ssq), 1e-12f);
            invS[r] = inv;
            s2S[r] = ssq * inv * inv;
        }
    }
    __syncthreads();

    const int lane = tid & 63, wv = tid >> 6;
    const int lo = lane & 15, quad = lane >> 4;

    // B-frags: this wave's token tile (col = lo, k = quad*8 + kh*32)
    bf16x8 Bh[2], Bm[2], Bl[2];
    {
        const int row = wv * 16 + lo;
#pragma unroll
        for (int kh = 0; kh < 2; kh++) {
            const int src = QD_ADDR(row, kh * 4 + quad);
            Bh[kh] = *(const bf16x8*)(qh + src);
            Bm[kh] = *(const bf16x8*)(qm + src);
            Bl[kh] = *(const bf16x8*)(ql + src);
        }
    }

    f32x4 acc[4];
#pragma unroll
    for (int ct = 0; ct < 4; ct++) {
        bf16x8 Ah[2], Am[2], Al[2];
#pragma unroll
        for (int kh = 0; kh < 2; kh++) {
            const int src = QD_ADDR(ct * 16 + lo, kh * 4 + quad);
            Ah[kh] = *(const bf16x8*)(ah + src);
            Am[kh] = *(const bf16x8*)(am + src);
            Al[kh] = *(const bf16x8*)(al + src);
        }
        f32x4 a = (f32x4){0.f, 0.f, 0.f, 0.f};
        // ~2^-24 terms
        a = MFMA(Al[0], Bm[0], a); a = MFMA(Al[1], Bm[1], a);
        a = MFMA(Am[0], Bl[0], a); a = MFMA(Am[1], Bl[1], a);
        // ~2^-16 terms
        a = MFMA(Am[0], Bm[0], a); a = MFMA(Am[1], Bm[1], a);
        a = MFMA(Ah[0], Bl[0], a); a = MFMA(Ah[1], Bl[1], a);
        a = MFMA(Al[0], Bh[0], a); a = MFMA(Al[1], Bh[1], a);
        // ~2^-8 terms
        a = MFMA(Am[0], Bh[0], a); a = MFMA(Am[1], Bh[1], a);
        a = MFMA(Ah[0], Bm[0], a); a = MFMA(Ah[1], Bm[1], a);
        // main term
        a = MFMA(Ah[0], Bh[0], a); a = MFMA(Ah[1], Bh[1], a);
        acc[ct] = a;
    }

    // epilogue: keys + per-token argmax (for loss only)
    const int tok = wv * 16 + lo;
    const float inv = invS[tok];
    float rawmax = -3.0e38f; int cbest = 0;
    u32* kout = keys + (size_t)bh * NC * TT + (size_t)(t0 + tok);
#pragma unroll
    for (int ct = 0; ct < 4; ct++)
#pragma unroll
        for (int r = 0; r < 4; r++) {
            const float raw = acc[ct][r];
            const int c = ct * 16 + quad * 4 + r;
            if (raw > rawmax) { rawmax = raw; cbest = c; }
            kout[(size_t)c * TT] = fixkey32(raw * inv);
        }

    // merge argmax across quads (lanes lo+16q share token lo)
#pragma unroll
    for (int off = 16; off < 64; off <<= 1) {
        const float ov = __shfl_xor(rawmax, off);
        const int   oc = __shfl_xor(cbest, off);
        if (ov > rawmax || (ov == rawmax && oc < cbest)) { rawmax = ov; cbest = oc; }
    }
    double lt_lane = 0.0;
    if (quad == 0)
        lt_lane = (double)(s2S[tok] + mn2S[cbest] - 2.0f * rawmax * inv);

    // block loss reduction
#pragma unroll
    for (int o = 32; o; o >>= 1) lt_lane += __shfl_xor(lt_lane, o);
    if (lane == 0) red[wv] = lt_lane;
    __syncthreads();
    if (tid == 0) atomicAdd(lossa, red[0] + red[1] + red[2] + red[3]);
}

// ---------------------------------------------------------------------------
// Kernel 2: top-128 per (bh,c), 8-bit radix select on u32 fixed-point keys.
// ---------------------------------------------------------------------------
__global__ __launch_bounds__(256) void k_topk(
    const u32* __restrict__ keys, int* __restrict__ indices,
    unsigned int* __restrict__ cnt, unsigned short* __restrict__ inv)
{
    __shared__ unsigned int hist[4][256];    // 4 KB
    __shared__ int wsum[8];
    __shared__ int bc_bin, bc_rank, bc_cnt;

    const int bhc = blockIdx.x, tid = threadIdx.x;
    const int wv = tid >> 6, lane = tid & 63;
    const int bh = bhc >> 6;

    u32 key[32];
    {
        const uint4* p = (const uint4*)(keys + (size_t)bhc * TT + tid * 32);
#pragma unroll
        for (int i = 0; i < 8; i++) {
            uint4 u = p[i];
            key[4*i] = u.x; key[4*i+1] = u.y; key[4*i+2] = u.z; key[4*i+3] = u.w;
        }
    }

    u32 thr = 0;
    int need = 128, gshift = 24, prevShift = 0;
    unsigned int* hb = &hist[0][0];

    for (int level = 0; level < 4; level++) {
        const int shift = 24 - 8 * level;
        hb[tid] = 0; hb[tid + 256] = 0; hb[tid + 512] = 0; hb[tid + 768] = 0;
        __syncthreads();
        unsigned int* hw = hist[wv];
        if (level == 0) {
#pragma unroll
            for (int i = 0; i < 32; i++)
                atomicAdd(&hw[key[i] >> 24], 1u);
        } else {
            const u32 pv = thr >> prevShift;
#pragma unroll
            for (int i = 0; i < 32; i++)
                if ((key[i] >> prevShift) == pv)
                    atomicAdd(&hw[(key[i] >> shift) & 255u], 1u);
        }
        __syncthreads();

        const int b = 255 - tid;
        const int c = hist[0][b] + hist[1][b] + hist[2][b] + hist[3][b];
        int incl = c;
#pragma unroll
        for (int o = 1; o < 64; o <<= 1) {
            const int v = __shfl_up(incl, o);
            if (lane >= o) incl += v;
        }
        if (lane == 63) wsum[wv] = incl;
        __syncthreads();
        int above = incl - c;
        for (int wj = 0; wj < wv; wj++) above += wsum[wj];
        if (above < need && above + c >= need) {
            bc_bin = b; bc_rank = above; bc_cnt = c;
        }
        __syncthreads();
        thr |= ((u32)bc_bin) << shift;
        need -= bc_rank;
        gshift = shift;
        prevShift = shift;
        if (bc_cnt == need || shift == 0) break;
    }

    // ordered emission + inverse map
    const u32 tg = thr >> gshift;
    int cgt = 0, ceq = 0;
#pragma unroll
    for (int i = 0; i < 32; i++) {
        const u32 kg = key[i] >> gshift;
        cgt += (kg > tg) ? 1 : 0;
        ceq += (kg == tg) ? 1 : 0;
    }
    int ig = cgt, ie = ceq;
#pragma unroll
    for (int o = 1; o < 64; o <<= 1) {
        const int vg = __shfl_up(ig, o);
        const int ve = __shfl_up(ie, o);
        if (lane >= o) { ig += vg; ie += ve; }
    }
    if (lane == 63) { wsum[wv] = ig; wsum[4 + wv] = ie; }
    __syncthreads();
    int pgt = ig - cgt, peq = ie - ceq;
    for (int wj = 0; wj < wv; wj++) { pgt += wsum[wj]; peq += wsum[4 + wj]; }

    const int rneed = need;
    int* outp = indices + bhc * WW;
    unsigned int* cntb = cnt + (bh << 13);
    unsigned short* invb = inv + (((size_t)bh << 13) * INVCAP);
    const int cbase = (bhc & 63) * WW;
    int g = 0, e = 0;
#pragma unroll
    for (int i = 0; i < 32; i++) {
        const int tok = tid * 32 + i;
        const u32 kg = key[i] >> gshift;
        if (kg > tg) {
            const int tb = (peq + e < rneed) ? (peq + e) : rneed;
            const int wpos = pgt + g + tb;
            outp[wpos] = tok;
            const unsigned int pos = atomicAdd(&cntb[tok], 1u);
            if (pos < INVCAP) invb[(size_t)tok * INVCAP + pos] = (unsigned short)(cbase + wpos);
            g++;
        } else if (kg == tg) {
            if (peq + e < rneed) {
                const int wpos = pgt + g + peq + e;
                outp[wpos] = tok;
                const unsigned int pos = atomicAdd(&cntb[tok], 1u);
                if (pos < INVCAP) invb[(size_t)tok * INVCAP + pos] = (unsigned short)(cbase + wpos);
            }
            e++;
        }
    }
}

// ---------------------------------------------------------------------------
// Kernel 3: per-(bh,c) local attention, MFMA bf16. 512 threads = 8 waves.
// NTILE=4 tiles per block (grid 512 = exactly 2 blocks/CU, no dispatch tail,
// same bh per block). Single-buffered reg pipeline: next tile's idx+q loads
// issue after S1 (q regs dead post-staging), next v loads issue after the vt
// write — each hides under a full compute phase. rs accesses are wave-
// internal (R/bias/P/PV-pa all touch wave-own rows) so only uv/invs need the
// added S4 barrier. LDS 52736 B unchanged.
// ---------------------------------------------------------------------------
#define QS_ADDR(row, gi) (((row) << 6) + ((((gi) ^ ((row) & 7))) << 3))

__global__ __launch_bounds__(512) void k_attn(
    const float* __restrict__ qk, const float* __restrict__ vin,
    const __bf16* __restrict__ relb, const int* __restrict__ indices,
    float* __restrict__ bo)
{
    __shared__ __attribute__((aligned(16))) __bf16 uv[64 * 136];   // qs / later v^T
    __shared__ __attribute__((aligned(16))) __bf16 rs[128 * 136];  // R; later P
    __shared__ float invs[128];

    const int tid  = threadIdx.x;
    const int lane = tid & 63;
    const int wv   = tid >> 6;
    const int lo   = lane & 15;
    const int quad = lane >> 4;
    const int rbase = wv * 16;

    const int bhc0 = blockIdx.x * NTILE;
    const int bh   = bhc0 >> 6;
    const int h    = bh & 7;

    const int r  = tid >> 2;          // row 0..127
    const int qp = tid & 3;           // 16-float segment

    // ---- prefetch tile 0: idx -> q,v rows ----
    float4 q0, q1, q2, q3, v0, v1, v2, v3;
    {
        const int idx0 = indices[bhc0 * WW + r];
        const size_t ro = ((size_t)bh * TT + idx0) * DD + qp * 16;
        const float4* qsrc = (const float4*)(qk + ro);
        q0 = qsrc[0]; q1 = qsrc[1]; q2 = qsrc[2]; q3 = qsrc[3];
        const float4* vsrc = (const float4*)(vin + ro);
        v0 = vsrc[0]; v1 = vsrc[1]; v2 = vsrc[2]; v3 = vsrc[3];
    }

    for (int t = 0; t < NTILE; t++) {
        const int bhc = bhc0 + t;

        // ---- stage q -> uv (swizzled) + row inv-norms ----
        {
            float ssq = q0.x*q0.x + q0.y*q0.y + q0.z*q0.z + q0.w*q0.w
                      + q1.x*q1.x + q1.y*q1.y + q1.z*q1.z + q1.w*q1.w
                      + q2.x*q2.x + q2.y*q2.y + q2.z*q2.z + q2.w*q2.w
                      + q3.x*q3.x + q3.y*q3.y + q3.z*q3.z + q3.w*q3.w;
            ssq += __shfl_xor(ssq, 1);
            ssq += __shfl_xor(ssq, 2);
            if (qp == 0) invs[r] = 1.0f / fmaxf(sqrtf(ssq), 1e-12f);
            bf16x8 va, vb;
            va[0]=(__bf16)q0.x; va[1]=(__bf16)q0.y; va[2]=(__bf16)q0.z; va[3]=(__bf16)q0.w;
            va[4]=(__bf16)q1.x; va[5]=(__bf16)q1.y; va[6]=(__bf16)q1.z; va[7]=(__bf16)q1.w;
            vb[0]=(__bf16)q2.x; vb[1]=(__bf16)q2.y; vb[2]=(__bf16)q2.z; vb[3]=(__bf16)q2.w;
            vb[4]=(__bf16)q3.x; vb[5]=(__bf16)q3.y; vb[6]=(__bf16)q3.z; vb[7]=(__bf16)q3.w;
            *(bf16x8*)(uv + QS_ADDR(r, qp * 2))     = va;
            *(bf16x8*)(uv + QS_ADDR(r, qp * 2 + 1)) = vb;
        }
        __syncthreads();   // S1: qs + invs complete

        // ---- prefetch next tile's idx + q (q regs now dead) ----
        int nidx = 0;
        if (t + 1 < NTILE) {
            nidx = indices[(bhc + 1) * WW + r];
            const float4* qn = (const float4*)(qk + ((size_t)bh * TT + nidx) * DD + qp * 16);
            q0 = qn[0]; q1 = qn[1]; q2 = qn[2]; q3 = qn[3];
        }

        f32x4 acc[8];

        // ---- R = Q * W^T (W pre-cast bf16, direct 16B loads) ----
#pragma unroll
        for (int nt = 0; nt < 8; nt++) acc[nt] = (f32x4){0.f, 0.f, 0.f, 0.f};
#pragma unroll
        for (int k0 = 0; k0 < 64; k0 += 32) {
            bf16x8 qa = *(const bf16x8*)(uv + QS_ADDR(rbase + lo, (k0 >> 3) + quad));
#pragma unroll
            for (int nt = 0; nt < 8; nt++) {
                const bf16x8 wb = *(const bf16x8*)(relb + ((nt * 16 + lo) * 8 + h) * 64 + k0 + quad * 8);
                acc[nt] = MFMA(qa, wb, acc[nt]);
            }
        }
#pragma unroll
        for (int nt = 0; nt < 8; nt++)
#pragma unroll
            for (int rg = 0; rg < 4; rg++)
                rs[(rbase + quad * 4 + rg) * 136 + nt * 16 + lo] = (__bf16)acc[nt][rg];

        // ---- dots = (Q*Q^T) * inv_j * scale ----
#pragma unroll
        for (int nt = 0; nt < 8; nt++) acc[nt] = (f32x4){0.f, 0.f, 0.f, 0.f};
#pragma unroll
        for (int k0 = 0; k0 < 64; k0 += 32) {
            bf16x8 qa = *(const bf16x8*)(uv + QS_ADDR(rbase + lo, (k0 >> 3) + quad));
#pragma unroll
            for (int nt = 0; nt < 8; nt++) {
                bf16x8 qb = *(const bf16x8*)(uv + QS_ADDR(nt * 16 + lo, (k0 >> 3) + quad));
                acc[nt] = MFMA(qa, qb, acc[nt]);
            }
        }

        float inv_j[8];
#pragma unroll
        for (int nt = 0; nt < 8; nt++) inv_j[nt] = invs[nt * 16 + lo];

        // bias (shifted rel, wave-own rows of rs) + self-mask
#pragma unroll
        for (int rg = 0; rg < 4; rg++) {
            const int i = rbase + quad * 4 + rg;
#pragma unroll
            for (int nt = 0; nt < 8; nt++) {
                const int j = nt * 16 + lo;
                float val = acc[nt][rg] * inv_j[nt] * SCALE;
                if (j <= i) val += SCALE * (float)rs[i * 136 + (j + 127 - i)];
                if (j == i) val = -50000.0f;
                acc[nt][rg] = val;
            }
        }

        // row softmax -> P into rs (wave-own rows)
#pragma unroll
        for (int rg = 0; rg < 4; rg++) {
            float m = -3.0e38f;
#pragma unroll
            for (int nt = 0; nt < 8; nt++) m = fmaxf(m, acc[nt][rg]);
#pragma unroll
            for (int msk = 1; msk < 16; msk <<= 1) m = fmaxf(m, __shfl_xor(m, msk));
            float s = 0.f;
#pragma unroll
            for (int nt = 0; nt < 8; nt++) {
                const float e = __expf(acc[nt][rg] - m);
                acc[nt][rg] = e; s += e;
            }
#pragma unroll
            for (int msk = 1; msk < 16; msk <<= 1) s += __shfl_xor(s, msk);
            const float is = 1.0f / s;
            const int i = rbase + quad * 4 + rg;
#pragma unroll
            for (int nt = 0; nt < 8; nt++)
                rs[i * 136 + nt * 16 + lo] = (__bf16)(acc[nt][rg] * is);
        }
        __syncthreads();   // S2: all cross-wave reads of uv(q) done

        // ---- v (from regs) transposed into uv: vt[d][j], stride 136 ----
        __bf16* vt = uv;
        vt[(qp * 16 +  0) * 136 + r] = (__bf16)v0.x;
        vt[(qp * 16 +  1) * 136 + r] = (__bf16)v0.y;
        vt[(qp * 16 +  2) * 136 + r] = (__bf16)v0.z;
        vt[(qp * 16 +  3) * 136 + r] = (__bf16)v0.w;
        vt[(qp * 16 +  4) * 136 + r] = (__bf16)v1.x;
        vt[(qp * 16 +  5) * 136 + r] = (__bf16)v1.y;
        vt[(qp * 16 +  6) * 136 + r] = (__bf16)v1.z;
        vt[(qp * 16 +  7) * 136 + r] = (__bf16)v1.w;
        vt[(qp * 16 +  8) * 136 + r] = (__bf16)v2.x;
        vt[(qp * 16 +  9) * 136 + r] = (__bf16)v2.y;
        vt[(qp * 16 + 10) * 136 + r] = (__bf16)v2.z;
        vt[(qp * 16 + 11) * 136 + r] = (__bf16)v2.w;
        vt[(qp * 16 + 12) * 136 + r] = (__bf16)v3.x;
        vt[(qp * 16 + 13) * 136 + r] = (__bf16)v3.y;
        vt[(qp * 16 + 14) * 136 + r] = (__bf16)v3.z;
        vt[(qp * 16 + 15) * 136 + r] = (__bf16)v3.w;

        // ---- prefetch next tile's v (v regs now dead) ----
        if (t + 1 < NTILE) {
            const float4* vn = (const float4*)(vin + ((size_t)bh * TT + nidx) * DD + qp * 16);
            v0 = vn[0]; v1 = vn[1]; v2 = vn[2]; v3 = vn[3];
        }
        __syncthreads();   // S3: vt complete (cross-wave)

        // ---- bo = P * V ----
        f32x4 accO[4];
#pragma unroll
        for (int nt = 0; nt < 4; nt++) accO[nt] = (f32x4){0.f, 0.f, 0.f, 0.f};
#pragma unroll
        for (int k0 = 0; k0 < 128; k0 += 32) {
            bf16x8 pa = *(const bf16x8*)(rs + (rbase + lo) * 136 + k0 + quad * 8);
#pragma unroll
            for (int nt = 0; nt < 4; nt++) {
                bf16x8 vb = *(const bf16x8*)(vt + (nt * 16 + lo) * 136 + k0 + quad * 8);
                accO[nt] = MFMA(pa, vb, accO[nt]);
            }
        }

        // ---- dense store ----
        float* bb = bo + (size_t)bhc * (WW * DD);
#pragma unroll
        for (int rg = 0; rg < 4; rg++) {
            const int i = rbase + quad * 4 + rg;
#pragma unroll
            for (int nt = 0; nt < 4; nt++)
                bb[(size_t)i * DD + nt * 16 + lo] = accO[nt][rg];
        }
        __syncthreads();   // S4: vt reads done; next tile may overwrite uv/invs
    }
}

// ---------------------------------------------------------------------------
// Kernel 4: per-token gather-sum of dense bo rows + normalize (+ loss).
// Slots 0..7 prefetched via one 16-B load -> up to 8 INDEPENDENT row gathers
// issue in parallel (was a serial dependent chain). Tail loop only for nc>8.
// ---------------------------------------------------------------------------
__global__ __launch_bounds__(256) void k_out(
    const float* __restrict__ bo, const unsigned int* __restrict__ cnt,
    const unsigned short* __restrict__ inv, const double* __restrict__ lossa,
    float* __restrict__ out)
{
    const int tid = threadIdx.x;
    const int g = blockIdx.x * 16 + (tid >> 4);      // global token 0..262143
    const int l = tid & 15;
    const int bh = g >> 13;
    const unsigned int n = cnt[g];
    const int nc = (n < (unsigned)INVCAP) ? (int)n : INVCAP;
    const unsigned short* ip = inv + (size_t)g * INVCAP;
    const float* bbase = bo + (((size_t)bh << 13) * DD) + l * 4;

    // prefetch first 8 slot ids in one 16-B load (inv rows are 48 B, 16-aligned)
    const uint4 ipv = *(const uint4*)ip;
    const int s0 = ipv.x & 0xffff, s1 = ipv.x >> 16;
    const int s2 = ipv.y & 0xffff, s3 = ipv.y >> 16;
    const int s4 = ipv.z & 0xffff, s5 = ipv.z >> 16;
    const int s6 = ipv.w & 0xffff, s7 = ipv.w >> 16;

    float4 a0 = {0.f,0.f,0.f,0.f}, a1 = a0, a2 = a0, a3 = a0;
    float4 a4 = a0, a5 = a0, a6 = a0, a7 = a0;
    if (nc > 0) a0 = *(const float4*)(bbase + (size_t)s0 * DD);
    if (nc > 1) a1 = *(const float4*)(bbase + (size_t)s1 * DD);
    if (nc > 2) a2 = *(const float4*)(bbase + (size_t)s2 * DD);
    if (nc > 3) a3 = *(const float4*)(bbase + (size_t)s3 * DD);
    if (nc > 4) a4 = *(const float4*)(bbase + (size_t)s4 * DD);
    if (nc > 5) a5 = *(const float4*)(bbase + (size_t)s5 * DD);
    if (nc > 6) a6 = *(const float4*)(bbase + (size_t)s6 * DD);
    if (nc > 7) a7 = *(const float4*)(bbase + (size_t)s7 * DD);

    float4 s;
    s.x = ((a0.x + a1.x) + (a2.x + a3.x)) + ((a4.x + a5.x) + (a6.x + a7.x));
    s.y = ((a0.y + a1.y) + (a2.y + a3.y)) + ((a4.y + a5.y) + (a6.y + a7.y));
    s.z = ((a0.z + a1.z) + (a2.z + a3.z)) + ((a4.z + a5.z) + (a6.z + a7.z));
    s.w = ((a0.w + a1.w) + (a2.w + a3.w)) + ((a4.w + a5.w) + (a6.w + a7.w));

    for (int e = 8; e < nc; e++) {
        const int slot = ip[e];
        const float4 v4 = *(const float4*)(bbase + (size_t)slot * DD);
        s.x += v4.x; s.y += v4.y; s.z += v4.z; s.w += v4.w;
    }

    const float r = 1.0f / ((float)n + 1e-5f);
    s.x *= r; s.y *= r; s.z *= r; s.w *= r;
    *(float4*)(out + (size_t)g * DD + l * 4) = s;
    if (g == 0 && l == 0) out[16777216] = (float)(lossa[0] * (0.0001 / 16777216.0));
}

// ---------------------------------------------------------------------------
extern "C" void kernel_launch(void* const* d_in, const int* in_sizes, int n_in,
                              void* d_out, int out_size, void* d_ws, size_t ws_size,
                              hipStream_t stream) {
    (void)in_sizes; (void)n_in; (void)ws_size; (void)out_size;
    const float* qk    = (const float*)d_in[0];
    const float* v     = (const float*)d_in[1];
    const float* means = (const float*)d_in[2];
    const float* rel_w = (const float*)d_in[3];
    float* out = (float*)d_out;

    // ws layout:
    //   [keys u32 67MB]           (bo 67MB aliases it after k_topk)
    //   [idx 1MB]
    //   [cnt 1MB][lossa pad 4KB]  (memset region)
    //   [inv u16 cap24 12.6MB]
    //   [relb bf16 128KB]
    char* ws = (char*)d_ws;
    const size_t KEYS_B = (size_t)BHN * NC * TT * 4;        // 67108864
    const size_t IDX_B  = (size_t)BHN * NC * WW * 4;        // 1048576
    const size_t CNT_B  = (size_t)BHN * TT * 4;             // 1048576
    const size_t INV_B  = (size_t)BHN * TT * INVCAP * 2;    // 12582912
    u32*            keys  = (u32*)ws;
    float*          bo    = (float*)ws;                     // alias, post-k_topk
    int*            idx   = (int*)(ws + KEYS_B);
    unsigned int*   cnt   = (unsigned int*)(ws + KEYS_B + IDX_B);
    double*         lossa = (double*)(ws + KEYS_B + IDX_B + CNT_B);
    unsigned short* inv   = (unsigned short*)(ws + KEYS_B + IDX_B + CNT_B + 4096);
    __bf16*         relb  = (__bf16*)(ws + KEYS_B + IDX_B + CNT_B + 4096 + INV_B);

    hipMemsetAsync(ws + KEYS_B + IDX_B, 0, CNT_B + 4096, stream);

    k_dists<<<dim3(BHN, TT / DTPB), 256, 0, stream>>>(qk, means, rel_w, relb, keys, lossa);
    k_topk<<<BHN * NC, 256, 0, stream>>>(keys, idx, cnt, inv);
    k_attn<<<BHN * NC / NTILE, 512, 0, stream>>>(qk, v, relb, idx, bo);
    k_out<<<BHN * TT / 16, 256, 0, stream>>>(bo, cnt, inv, lossa, out);
}